// Round 13
// baseline (961.576 us; speedup 1.0000x reference)
//
#include <hip/hip_runtime.h>
#include <hip/hip_bf16.h>

#define E_TOT   1600000
#define NN      50000
#define K1      176     // msg MLP input dim (2*64+32+16)
#define H1      128     // MSG_HID
#define HS2     136     // act row stride (ushorts), 272B, 16B aligned
#define NGC     (E_TOT / 32)   // 50000 exact 32-edge chunks
#define NB      196            // scan blocks (196*256 >= 50001)
#define NT_NODE ((NN + 63) / 64)
#define EW      8              // waves per edge-kernel block (512 thr — >512 spills!)

typedef __attribute__((ext_vector_type(8))) short bf16x8;
typedef __attribute__((ext_vector_type(4))) float f32x4;
typedef unsigned short u16;
typedef unsigned int u32;

__device__ __forceinline__ u16 f2bf(float x) {
  return __builtin_bit_cast(u16, __float2bfloat16(x));   // native RNE cvt
}
__device__ __forceinline__ u32 pk2bf(float lo, float hi) {
  return (u32)f2bf(lo) | ((u32)f2bf(hi) << 16);
}
__device__ __forceinline__ float silu_f(float x) { return x / (1.0f + __expf(-x)); }

__device__ __forceinline__ bf16x8 ldf8(const float* __restrict__ p) {
  float4 a = ((const float4*)p)[0];
  float4 b = ((const float4*)p)[1];
  bf16x8 r;
  r[0] = (short)f2bf(a.x); r[1] = (short)f2bf(a.y);
  r[2] = (short)f2bf(a.z); r[3] = (short)f2bf(a.w);
  r[4] = (short)f2bf(b.x); r[5] = (short)f2bf(b.y);
  r[6] = (short)f2bf(b.z); r[7] = (short)f2bf(b.w);
  return r;
}

struct Feats { bf16x8 s0a, s0b, s1a, s1b, d0a, d0b, d1a, d1b, e0, e1; };

__device__ __forceinline__ void load_feats(Feats& f, int use16,
    const u16* __restrict__ nf16, const float* __restrict__ nf,
    const float* __restrict__ ef,
    int s0, int s1, int d0, int d1, int e0i, int e1i, int g8)
{
  if (use16) {
    f.s0a = *(const bf16x8*)(nf16 + (size_t)s0*64 + g8);
    f.s0b = *(const bf16x8*)(nf16 + (size_t)s0*64 + 32 + g8);
    f.s1a = *(const bf16x8*)(nf16 + (size_t)s1*64 + g8);
    f.s1b = *(const bf16x8*)(nf16 + (size_t)s1*64 + 32 + g8);
    f.d0a = *(const bf16x8*)(nf16 + (size_t)d0*64 + g8);
    f.d0b = *(const bf16x8*)(nf16 + (size_t)d0*64 + 32 + g8);
    f.d1a = *(const bf16x8*)(nf16 + (size_t)d1*64 + g8);
    f.d1b = *(const bf16x8*)(nf16 + (size_t)d1*64 + 32 + g8);
  } else {
    f.s0a = ldf8(nf + (size_t)s0*64 + g8);
    f.s0b = ldf8(nf + (size_t)s0*64 + 32 + g8);
    f.s1a = ldf8(nf + (size_t)s1*64 + g8);
    f.s1b = ldf8(nf + (size_t)s1*64 + 32 + g8);
    f.d0a = ldf8(nf + (size_t)d0*64 + g8);
    f.d0b = ldf8(nf + (size_t)d0*64 + 32 + g8);
    f.d1a = ldf8(nf + (size_t)d1*64 + g8);
    f.d1b = ldf8(nf + (size_t)d1*64 + 32 + g8);
  }
  if (g8 < 16) {                      // edge_feat fp32 (64B rows = same granule)
    f.e0 = ldf8(ef + (size_t)e0i*16 + g8);
    f.e1 = ldf8(ef + (size_t)e1i*16 + g8);
  } else { f.e0 = (bf16x8){0,0,0,0,0,0,0,0}; f.e1 = f.e0; }
}

// ---------------------------------------------------------------------------
// Fused prep: node cvt + weight fragment tables + dst histogram +
// msg_tot zero + out_coord=coord.
// ---------------------------------------------------------------------------
__global__ void prep_k(const float* __restrict__ nf, u16* __restrict__ nf16,
                       const int* __restrict__ eidx, int* __restrict__ count,
                       float* __restrict__ msg_tot,
                       const float* __restrict__ coord, float* __restrict__ out_coord,
                       const float* __restrict__ w1_msg, const float* __restrict__ w2_msg,
                       const float* __restrict__ w1_mov,
                       u16* __restrict__ w1g, u16* __restrict__ w2g,
                       u16* __restrict__ w3g, int use16) {
  const int tid = blockIdx.x * blockDim.x + threadIdx.x;
  const int stride = gridDim.x * blockDim.x;
  if (use16) {
    for (int i = tid; i < NN*64/4; i += stride) {
      float4 v = ((const float4*)nf)[i];
      uint2 p = { pk2bf(v.x, v.y), pk2bf(v.z, v.w) };
      ((uint2*)nf16)[i] = p;
    }
  }
  // weight fragment tables (permuted n-maps), 73.7 KB total -> L2 resident
  for (int i = tid; i < 6*8*64*8; i += stride) {
    int j = i & 7, l = (i >> 3) & 63, nt = (i >> 9) & 7, kb = i >> 12;
    int k = kb*32 + (l >> 4)*8 + j;
    w1g[i] = f2bf(k < K1 ? w1_msg[k*H1 + 8*(l & 15) + nt] : 0.0f);
  }
  for (int i = tid; i < 4*4*64*8; i += stride) {
    int j = i & 7, l = (i >> 3) & 63, nt = (i >> 9) & 3, kb = i >> 11;
    w2g[i] = f2bf(w2_msg[(kb*32 + (l >> 4)*8 + j)*64 + 4*(l & 15) + nt]);
  }
  for (int i = tid; i < 2*4*64*8; i += stride) {
    int j = i & 7, l = (i >> 3) & 63, nt = (i >> 9) & 3, kb = i >> 11;
    w3g[i] = f2bf(w1_mov[(kb*32 + (l >> 4)*8 + j)*64 + 4*(l & 15) + nt]);
  }
  const float4 z4 = {0.f, 0.f, 0.f, 0.f};
  for (int i = tid; i < NN*64/4; i += stride) ((float4*)msg_tot)[i] = z4;
  for (int i = tid; i < NN*3; i += stride) out_coord[i] = coord[i];
  for (int i = tid; i < E_TOT; i += stride) atomicAdd(&count[eidx[E_TOT + i]], 1);
}

__global__ __launch_bounds__(256) void scanA_k(const int* __restrict__ count,
                                               int* __restrict__ bsum) {
  __shared__ int sm[256];
  int idx = blockIdx.x * 256 + threadIdx.x;
  sm[threadIdx.x] = (idx < NN) ? count[idx] : 0;
  __syncthreads();
  for (int off = 128; off > 0; off >>= 1) {
    if (threadIdx.x < off) sm[threadIdx.x] += sm[threadIdx.x + off];
    __syncthreads();
  }
  if (threadIdx.x == 0) bsum[blockIdx.x] = sm[0];
}

__global__ __launch_bounds__(256) void scanB_k(const int* __restrict__ bsum,
                                               int* __restrict__ boff) {
  __shared__ int sm[256];
  int t = threadIdx.x;
  int v = (t < NB) ? bsum[t] : 0;
  sm[t] = v; __syncthreads();
  for (int off = 1; off < 256; off <<= 1) {
    int x = (t >= off) ? sm[t - off] : 0;
    __syncthreads();
    sm[t] += x;
    __syncthreads();
  }
  boff[t] = sm[t] - v;                 // exclusive prefix of block sums
}

__global__ __launch_bounds__(256) void scanC_k(const int* __restrict__ count,
                                               const int* __restrict__ boff,
                                               int* __restrict__ cursor) {
  __shared__ int sm[256];
  int idx = blockIdx.x * 256 + threadIdx.x, t = threadIdx.x;
  int v = (idx < NN) ? count[idx] : 0;
  sm[t] = v; __syncthreads();
  for (int off = 1; off < 256; off <<= 1) {
    int x = (t >= off) ? sm[t - off] : 0;
    __syncthreads();
    sm[t] += x;
    __syncthreads();
  }
  if (idx < NN) cursor[idx] = boff[blockIdx.x] + sm[t] - v;
}

// scatter: write dst-sorted meta {src,dst,eid} + geo {rel.xyz, dist}
__global__ void scatter_k(const int* __restrict__ eidx,
                          const float* __restrict__ coord,
                          int* __restrict__ cursor,
                          int4* __restrict__ meta, float4* __restrict__ geo) {
  int i = blockIdx.x * blockDim.x + threadIdx.x;
  int stride = gridDim.x * blockDim.x;
  for (; i < E_TOT; i += stride) {
    int s = eidx[i];
    int d = eidx[E_TOT + i];
    int pos = atomicAdd(&cursor[d], 1);
    float rx = coord[(size_t)d*3+0] - coord[(size_t)s*3+0];
    float ry = coord[(size_t)d*3+1] - coord[(size_t)s*3+1];
    float rz = coord[(size_t)d*3+2] - coord[(size_t)s*3+2];
    float dist = sqrtf(rx*rx + ry*ry + rz*rz);
    meta[pos] = make_int4(s, d, i, 0);
    geo[pos]  = make_float4(rx, ry, rz, dist);
  }
}

// ---------------------------------------------------------------------------
// Edge kernel v13: weight fragments read from L2-resident GLOBAL tables
// (written by prep_k) -> LDS is act-only (69.6 KB) -> 2 blocks/CU =
// 4 waves/SIMD (2x issue capacity). Fully barrier-free. Grid 512.
// B n-maps: GEMM1 n = 8*(lane&15)+nt ; GEMM2/3 n = 4*(lane&15)+nt.
// A/B k-map (shared): k = 32*kb + (lane>>4)*8 + j  (permutation-safe).
// C/D: hw-col = lane&15, row = (lane>>4)*4 + reg   (HW-verified).
// ---------------------------------------------------------------------------
__global__ __launch_bounds__(512, 2) void egnn_edge(
    const float* __restrict__ node_feat, const float* __restrict__ edge_feat,
    const int4* __restrict__ meta, const float4* __restrict__ geo,
    const u16* __restrict__ w1g, const u16* __restrict__ w2g,
    const u16* __restrict__ w3g, const float* __restrict__ w2_mov,
    const u16* __restrict__ nf16, int use16,
    float* __restrict__ msg_tot, float* __restrict__ out_coord)
{
  __shared__ u16 act[EW][32*HS2];   // 69.6KB total — fits 2 blocks/CU

  const int t = threadIdx.x;
  const int lane = t & 63;
  const int wv = t >> 6;              // 0..7
  const int cl = lane & 15;
  const int g8 = (lane >> 4) * 8;
  const int orow4 = (lane >> 4) * 4;
  const int el = lane & 31;

  float w2m_r[4];
  #pragma unroll
  for (int nt = 0; nt < 4; ++nt) w2m_r[nt] = w2_mov[4*cl + nt];

  u16* const myact = &act[wv][0];
  const int NW = gridDim.x * EW;

  int g = blockIdx.x * EW + wv;
  if (g >= NGC) return;

  // ---- prologue: coalesced meta/geo + feature gathers ----
  int4  mm = meta[g*32 + el];
  float4 qq = geo[g*32 + el];
  int dv = mm.y;
  float rx = qq.x, ry = qq.y, rz = qq.z;
  float dist0 = __shfl(qq.w, cl), dist1 = __shfl(qq.w, 16 + cl);
  Feats cf;
  {
    int s0 = __shfl(mm.x, cl), s1 = __shfl(mm.x, 16 + cl);
    int d0 = __shfl(mm.y, cl), d1 = __shfl(mm.y, 16 + cl);
    int e0i = __shfl(mm.z, cl), e1i = __shfl(mm.z, 16 + cl);
    load_feats(cf, use16, nf16, node_feat, edge_feat,
               s0, s1, d0, d1, e0i, e1i, g8);
  }

  while (true) {
    const int gn = g + NW;
    const bool hn = gn < NGC;

    // ---- stage 0: next chunk's meta/geo (coalesced, no chain) ----
    int4 nm = make_int4(0,0,0,0);
    float4 nq = make_float4(0.f,0.f,0.f,0.f);
    if (hn) { nm = meta[gn*32 + el]; nq = geo[gn*32 + el]; }

    // ---- rbf fragments (current chunk) ----
    bf16x8 rbf0, rbf1;
    #pragma unroll
    for (int j = 0; j < 8; ++j) {
      float c = (float)(g8 + j) * (10.0f / 31.0f);
      float u0 = dist0 - c, u1 = dist1 - c;
      rbf0[j] = (short)f2bf(__expf(-10.0f * u0 * u0));
      rbf1[j] = (short)f2bf(__expf(-10.0f * u1 * u1));
    }

    // ---- GEMM1: h = silu(m_in @ W1)  [32x192]@[192x128] ----
    f32x4 acc1[2][8];
    #pragma unroll
    for (int rt = 0; rt < 2; ++rt)
      #pragma unroll
      for (int nt = 0; nt < 8; ++nt) acc1[rt][nt] = (f32x4){0.f,0.f,0.f,0.f};
    #pragma unroll
    for (int kb = 0; kb < 6; ++kb) {
      bf16x8 af0, af1;
      if      (kb == 0) { af0 = cf.s0a; af1 = cf.s1a; }
      else if (kb == 1) { af0 = cf.s0b; af1 = cf.s1b; }
      else if (kb == 2) { af0 = cf.d0a; af1 = cf.d1a; }
      else if (kb == 3) { af0 = cf.d0b; af1 = cf.d1b; }
      else if (kb == 4) { af0 = rbf0;   af1 = rbf1;   }
      else              { af0 = cf.e0;  af1 = cf.e1;  }
      #pragma unroll
      for (int nt = 0; nt < 8; ++nt) {
        bf16x8 bw = *(const bf16x8*)(w1g + ((kb*8 + nt)*64 + lane)*8);
        acc1[0][nt] = __builtin_amdgcn_mfma_f32_16x16x32_bf16(af0, bw, acc1[0][nt], 0, 0, 0);
        acc1[1][nt] = __builtin_amdgcn_mfma_f32_16x16x32_bf16(af1, bw, acc1[1][nt], 0, 0, 0);
      }
    }
    // packed epilogue: lane holds h[row][8*cl .. 8*cl+7] for 8 rows
    #pragma unroll
    for (int rt = 0; rt < 2; ++rt)
      #pragma unroll
      for (int r = 0; r < 4; ++r) {
        uint4 q;
        q.x = pk2bf(silu_f(acc1[rt][0][r]), silu_f(acc1[rt][1][r]));
        q.y = pk2bf(silu_f(acc1[rt][2][r]), silu_f(acc1[rt][3][r]));
        q.z = pk2bf(silu_f(acc1[rt][4][r]), silu_f(acc1[rt][5][r]));
        q.w = pk2bf(silu_f(acc1[rt][6][r]), silu_f(acc1[rt][7][r]));
        *(uint4*)(myact + (rt*16 + orow4 + r)*HS2 + 8*cl) = q;
      }
    asm volatile("" ::: "memory");    // h-writes before h-reads (program order)

    // ---- GEMM2: msg = silu(h @ W2)  [32x128]@[128x64] ----
    f32x4 acc2[2][4];
    #pragma unroll
    for (int rt = 0; rt < 2; ++rt)
      #pragma unroll
      for (int nt = 0; nt < 4; ++nt) acc2[rt][nt] = (f32x4){0.f,0.f,0.f,0.f};
    #pragma unroll
    for (int kb = 0; kb < 4; ++kb) {
      bf16x8 a0 = *(const bf16x8*)(myact + cl*HS2 + kb*32 + g8);
      bf16x8 a1 = *(const bf16x8*)(myact + (16 + cl)*HS2 + kb*32 + g8);
      #pragma unroll
      for (int nt = 0; nt < 4; ++nt) {
        bf16x8 bw = *(const bf16x8*)(w2g + ((kb*4 + nt)*64 + lane)*8);
        acc2[0][nt] = __builtin_amdgcn_mfma_f32_16x16x32_bf16(a0, bw, acc2[0][nt], 0, 0, 0);
        acc2[1][nt] = __builtin_amdgcn_mfma_f32_16x16x32_bf16(a1, bw, acc2[1][nt], 0, 0, 0);
      }
    }
    asm volatile("" ::: "memory");
    // mval regs (col = 4*cl+nt) + packed m -> act cols 0..63
    float mval[2][4][4];
    #pragma unroll
    for (int rt = 0; rt < 2; ++rt)
      #pragma unroll
      for (int r = 0; r < 4; ++r) {
        #pragma unroll
        for (int nt = 0; nt < 4; ++nt) mval[rt][nt][r] = silu_f(acc2[rt][nt][r]);
        uint2 q;
        q.x = pk2bf(mval[rt][0][r], mval[rt][1][r]);
        q.y = pk2bf(mval[rt][2][r], mval[rt][3][r]);
        *(uint2*)(myact + (rt*16 + orow4 + r)*HS2 + 4*cl) = q;
      }
    asm volatile("" ::: "memory");    // m-writes before m-reads

    // ---- stage 2: next chunk's feature gathers ----
    Feats nf_;
    if (hn) {
      int s0 = __shfl(nm.x, cl), s1 = __shfl(nm.x, 16 + cl);
      int d0 = __shfl(nm.y, cl), d1 = __shfl(nm.y, 16 + cl);
      int e0i = __shfl(nm.z, cl), e1i = __shfl(nm.z, 16 + cl);
      load_feats(nf_, use16, nf16, node_feat, edge_feat,
                 s0, s1, d0, d1, e0i, e1i, g8);
    }

    // ---- GEMM3: s = silu(msg @ W3) @ w2_mov ----
    f32x4 acc3[2][4];
    #pragma unroll
    for (int rt = 0; rt < 2; ++rt)
      #pragma unroll
      for (int nt = 0; nt < 4; ++nt) acc3[rt][nt] = (f32x4){0.f,0.f,0.f,0.f};
    #pragma unroll
    for (int kb = 0; kb < 2; ++kb) {
      bf16x8 a0 = *(const bf16x8*)(myact + cl*HS2 + kb*32 + g8);
      bf16x8 a1 = *(const bf16x8*)(myact + (16 + cl)*HS2 + kb*32 + g8);
      #pragma unroll
      for (int nt = 0; nt < 4; ++nt) {
        bf16x8 bw = *(const bf16x8*)(w3g + ((kb*4 + nt)*64 + lane)*8);
        acc3[0][nt] = __builtin_amdgcn_mfma_f32_16x16x32_bf16(a0, bw, acc3[0][nt], 0, 0, 0);
        acc3[1][nt] = __builtin_amdgcn_mfma_f32_16x16x32_bf16(a1, bw, acc3[1][nt], 0, 0, 0);
      }
    }
    float prt[2][4];
    #pragma unroll
    for (int rt = 0; rt < 2; ++rt)
      #pragma unroll
      for (int r = 0; r < 4; ++r) prt[rt][r] = 0.f;
    #pragma unroll
    for (int nt = 0; nt < 4; ++nt)
      #pragma unroll
      for (int rt = 0; rt < 2; ++rt)
        #pragma unroll
        for (int r = 0; r < 4; ++r)
          prt[rt][r] += silu_f(acc3[rt][nt][r]) * w2m_r[nt];
    #pragma unroll
    for (int off = 1; off < 16; off <<= 1)
      #pragma unroll
      for (int rt = 0; rt < 2; ++rt)
        #pragma unroll
        for (int r = 0; r < 4; ++r) prt[rt][r] += __shfl_xor(prt[rt][r], off, 64);

    // per-row rel vectors (broadcast once)
    float rxv[2][4], ryv[2][4], rzv[2][4];
    #pragma unroll
    for (int rt = 0; rt < 2; ++rt)
      #pragma unroll
      for (int r = 0; r < 4; ++r) {
        int row = rt*16 + orow4 + r;
        rxv[rt][r] = __shfl(rx, row);
        ryv[rt][r] = __shfl(ry, row);
        rzv[rt][r] = __shfl(rz, row);
      }

    // ---- segmented aggregation over dst-runs (rows sorted by dst) ----
    int start = 0;
    while (start < 32) {
      int node = __shfl(dv, start);
      unsigned long long b = __ballot(dv == node);
      unsigned m32 = (unsigned)b;
      unsigned rest = ~m32 & (0xFFFFFFFFu << start);
      int end = rest ? (__ffs(rest) - 1) : 32;

      float msum[4] = {0.f, 0.f, 0.f, 0.f};
      float sx = 0.f, sy = 0.f, sz = 0.f;
      #pragma unroll
      for (int rt = 0; rt < 2; ++rt)
        #pragma unroll
        for (int r = 0; r < 4; ++r) {
          int row = rt*16 + orow4 + r;
          float mk = (row >= start && row < end) ? 1.0f : 0.0f;
          #pragma unroll
          for (int nt = 0; nt < 4; ++nt) msum[nt] += mval[rt][nt][r] * mk;
          float s = prt[rt][r] * mk;
          sx += rxv[rt][r] * s; sy += ryv[rt][r] * s; sz += rzv[rt][r] * s;
        }
      #pragma unroll
      for (int nt = 0; nt < 4; ++nt) {
        msum[nt] += __shfl_xor(msum[nt], 16, 64);
        msum[nt] += __shfl_xor(msum[nt], 32, 64);
      }
      sx += __shfl_xor(sx, 16, 64); sx += __shfl_xor(sx, 32, 64);
      sy += __shfl_xor(sy, 16, 64); sy += __shfl_xor(sy, 32, 64);
      sz += __shfl_xor(sz, 16, 64); sz += __shfl_xor(sz, 32, 64);

      // register transpose: lane l takes column l (src lane l>>2, elem l&3)
      float t0 = __shfl(msum[0], lane >> 2);
      float t1 = __shfl(msum[1], lane >> 2);
      float t2 = __shfl(msum[2], lane >> 2);
      float t3 = __shfl(msum[3], lane >> 2);
      int sel = lane & 3;
      float val = sel == 0 ? t0 : (sel == 1 ? t1 : (sel == 2 ? t2 : t3));
      atomicAdd(&msg_tot[(size_t)node*64 + lane], val);   // 256B coalesced

      if (lane == 0) {
        atomicAdd(&out_coord[(size_t)node*3 + 0], sx);
        atomicAdd(&out_coord[(size_t)node*3 + 1], sy);
        atomicAdd(&out_coord[(size_t)node*3 + 2], sz);
      }
      start = end;
    }

    if (!hn) break;
    // ---- rotate pipeline ----
    g = gn;
    dv = nm.y;
    rx = nq.x; ry = nq.y; rz = nq.z;
    dist0 = __shfl(nq.w, cl); dist1 = __shfl(nq.w, 16 + cl);
    cf = nf_;
  }
}

// ---------------------------------------------------------------------------
// Node kernel (persistent): new_feat = node_feat + silu([f|msg]@W1n+b1)@W2n+b2
// ---------------------------------------------------------------------------
__global__ __launch_bounds__(256, 1) void egnn_node(
    const float* __restrict__ node_feat, const float* __restrict__ msg_tot,
    const float* __restrict__ w1n, const float* __restrict__ b1n,
    const float* __restrict__ w2n, const float* __restrict__ b2n,
    float* __restrict__ out_feat)
{
  __shared__ u16 w1f[4*8*64*8];   // 32KB  (n = 8*(l&15)+nt)
  __shared__ u16 w2f[4*4*64*8];   // 16KB  (n = 4*(l&15)+nt)
  __shared__ u16 a_lds[64*HS2];
  __shared__ u16 h_lds[64*HS2];
  __shared__ float b1s[128];
  __shared__ float b2s[64];

  const int t = threadIdx.x, lane = t & 63, wv = t >> 6;
  const int cl = lane & 15;
  const int row16 = wv*16 + cl;
  const int g8 = (lane >> 4) * 8;
  const int orow = wv*16 + (lane >> 4)*4;

  for (int i = t; i < 4*8*64*8; i += 256) {
    int j = i & 7, l = (i >> 3) & 63, nt = (i >> 9) & 7, kb = i >> 12;
    w1f[i] = f2bf(w1n[(kb*32 + (l >> 4)*8 + j)*128 + 8*(l & 15) + nt]);
  }
  for (int i = t; i < 4*4*64*8; i += 256) {
    int j = i & 7, l = (i >> 3) & 63, nt = (i >> 9) & 3, kb = i >> 11;
    w2f[i] = f2bf(w2n[(kb*32 + (l >> 4)*8 + j)*64 + 4*(l & 15) + nt]);
  }
  if (t < 128) b1s[t] = b1n[t];
  if (t < 64)  b2s[t] = b2n[t];

  for (int tile = blockIdx.x; tile < NT_NODE; tile += gridDim.x) {
    const int n0 = tile * 64;
    __syncthreads();                    // protect a_lds/h_lds reuse
    {
      const int nd = t >> 2, q = t & 3;
      const int gn = n0 + nd;
      u16* arow = a_lds + nd*HS2;
      if (gn < NN) {
        const float4* pf = (const float4*)(node_feat + (size_t)gn*64 + q*16);
        float4 vf = pf[0], vf2 = pf[1], vf3 = pf[2], vf4 = pf[3];
        uint4 qa = { pk2bf(vf.x, vf.y),  pk2bf(vf.z, vf.w),
                     pk2bf(vf2.x, vf2.y), pk2bf(vf2.z, vf2.w) };
        uint4 qb = { pk2bf(vf3.x, vf3.y), pk2bf(vf3.z, vf3.w),
                     pk2bf(vf4.x, vf4.y), pk2bf(vf4.z, vf4.w) };
        *(uint4*)(arow + q*16) = qa;
        *(uint4*)(arow + q*16 + 8) = qb;
        const float4* pm = (const float4*)(msg_tot + (size_t)gn*64 + q*16);
        float4 vm = pm[0], vm2 = pm[1], vm3 = pm[2], vm4 = pm[3];
        uint4 qc = { pk2bf(vm.x, vm.y),  pk2bf(vm.z, vm.w),
                     pk2bf(vm2.x, vm2.y), pk2bf(vm2.z, vm2.w) };
        uint4 qd = { pk2bf(vm3.x, vm3.y), pk2bf(vm3.z, vm3.w),
                     pk2bf(vm4.x, vm4.y), pk2bf(vm4.z, vm4.w) };
        *(uint4*)(arow + 64 + q*16) = qc;
        *(uint4*)(arow + 64 + q*16 + 8) = qd;
      } else {
        uint4 z = {0,0,0,0};
        *(uint4*)(arow + q*16) = z;  *(uint4*)(arow + q*16 + 8) = z;
        *(uint4*)(arow + 64 + q*16) = z; *(uint4*)(arow + 64 + q*16 + 8) = z;
      }
    }
    __syncthreads();
    {
      f32x4 acc[8];
      #pragma unroll
      for (int nt = 0; nt < 8; ++nt) acc[nt] = (f32x4){0.f,0.f,0.f,0.f};
      #pragma unroll
      for (int kb = 0; kb < 4; ++kb) {
        bf16x8 af = *(const bf16x8*)(a_lds + row16*HS2 + kb*32 + g8);
        #pragma unroll
        for (int nt = 0; nt < 8; ++nt) {
          bf16x8 bfv = *(const bf16x8*)(w1f + ((kb*8 + nt)*64 + lane)*8);
          acc[nt] = __builtin_amdgcn_mfma_f32_16x16x32_bf16(af, bfv, acc[nt], 0, 0, 0);
        }
      }
      #pragma unroll
      for (int r = 0; r < 4; ++r) {
        uint4 q;
        q.x = pk2bf(silu_f(acc[0][r] + b1s[8*cl+0]), silu_f(acc[1][r] + b1s[8*cl+1]));
        q.y = pk2bf(silu_f(acc[2][r] + b1s[8*cl+2]), silu_f(acc[3][r] + b1s[8*cl+3]));
        q.z = pk2bf(silu_f(acc[4][r] + b1s[8*cl+4]), silu_f(acc[5][r] + b1s[8*cl+5]));
        q.w = pk2bf(silu_f(acc[6][r] + b1s[8*cl+6]), silu_f(acc[7][r] + b1s[8*cl+7]));
        *(uint4*)(h_lds + (orow + r)*HS2 + 8*cl) = q;
      }
    }
    __syncthreads();
    {
      f32x4 acc[4];
      #pragma unroll
      for (int nt = 0; nt < 4; ++nt) acc[nt] = (f32x4){0.f,0.f,0.f,0.f};
      #pragma unroll
      for (int kb = 0; kb < 4; ++kb) {
        bf16x8 af = *(const bf16x8*)(h_lds + row16*HS2 + kb*32 + g8);
        #pragma unroll
        for (int nt = 0; nt < 4; ++nt) {
          bf16x8 bfv = *(const bf16x8*)(w2f + ((kb*4 + nt)*64 + lane)*8);
          acc[nt] = __builtin_amdgcn_mfma_f32_16x16x32_bf16(af, bfv, acc[nt], 0, 0, 0);
        }
      }
      #pragma unroll
      for (int r = 0; r < 4; ++r) {
        int row = orow + r, gn = n0 + row;
        if (gn < NN) {
          float4 base = *(const float4*)(node_feat + (size_t)gn*64 + 4*cl);
          float4 o;
          o.x = acc[0][r] + b2s[4*cl+0] + base.x;
          o.y = acc[1][r] + b2s[4*cl+1] + base.y;
          o.z = acc[2][r] + b2s[4*cl+2] + base.z;
          o.w = acc[3][r] + b2s[4*cl+3] + base.w;
          *(float4*)(out_feat + (size_t)gn*64 + 4*cl) = o;
        }
      }
    }
  }
}

extern "C" void kernel_launch(void* const* d_in, const int* in_sizes, int n_in,
                              void* d_out, int out_size, void* d_ws, size_t ws_size,
                              hipStream_t stream) {
  (void)in_sizes; (void)n_in; (void)out_size;
  const float* node_feat = (const float*)d_in[0];
  const float* coord     = (const float*)d_in[1];
  const float* edge_feat = (const float*)d_in[2];
  const int*   eidx      = (const int*)d_in[3];
  const float* w1_msg    = (const float*)d_in[4];
  const float* w2_msg    = (const float*)d_in[5];
  const float* w1_mov    = (const float*)d_in[6];
  const float* w2_mov    = (const float*)d_in[7];
  const float* w1n       = (const float*)d_in[9];
  const float* b1n       = (const float*)d_in[10];
  const float* w2n       = (const float*)d_in[11];
  const float* b2n       = (const float*)d_in[12];

  float* out_feat  = (float*)d_out;
  float* out_coord = out_feat + (size_t)NN * 64;

  // workspace layout (all 16B aligned)
  int*    count   = (int*)d_ws;                          // 50048
  int*    cursor  = count + 50048;                       // 50048
  int*    bsum    = cursor + 50048;                      // 1024
  int*    boff    = bsum + 1024;                         // 1024
  u16*    w1g     = (u16*)(boff + 1024);                 // 24576 u16
  u16*    w2g     = w1g + 6*8*64*8;                      // 8192 u16
  u16*    w3g     = w2g + 4*4*64*8;                      // 4096 u16 (tot 73.7KB)
  float*  msg_tot = (float*)(w3g + 2*4*64*8);            // 3.2M floats (12.8MB)
  int4*   meta    = (int4*)(msg_tot + (size_t)NN*64);    // 1.6M int4 (25.6MB)
  float4* geo     = (float4*)(meta + E_TOT);             // 1.6M float4 (25.6MB)
  u16*    nf16    = (u16*)(geo + E_TOT);                 // 3.2M u16 (6.4MB)
  const size_t need16 = (size_t)((char*)(nf16 + (size_t)NN*64) - (char*)d_ws);
  const int use16 = ws_size >= need16 ? 1 : 0;

  hipMemsetAsync(count, 0, NN * sizeof(int), stream);
  prep_k<<<2048, 256, 0, stream>>>(node_feat, nf16, eidx, count,
                                   msg_tot, coord, out_coord,
                                   w1_msg, w2_msg, w1_mov,
                                   w1g, w2g, w3g, use16);
  scanA_k<<<NB, 256, 0, stream>>>(count, bsum);
  scanB_k<<<1, 256, 0, stream>>>(bsum, boff);
  scanC_k<<<NB, 256, 0, stream>>>(count, boff, cursor);
  scatter_k<<<2048, 256, 0, stream>>>(eidx, coord, cursor, meta, geo);
  egnn_edge<<<512, 512, 0, stream>>>(node_feat, edge_feat, meta, geo,
      w1g, w2g, w3g, w2_mov, nf16, use16, msg_tot, out_coord);
  egnn_node<<<256, 256, 0, stream>>>(node_feat, msg_tot,
      w1n, b1n, w2n, b2n, out_feat);
}

// Round 14
// 584.983 us; speedup vs baseline: 1.6438x; 1.6438x over previous
//
#include <hip/hip_runtime.h>
#include <hip/hip_bf16.h>

#define E_TOT   1600000
#define NN      50000
#define K1      176     // msg MLP input dim (2*64+32+16)
#define H1      128     // MSG_HID
#define HS2     136     // act row stride (ushorts), 272B, 16B aligned
#define NGC     (E_TOT / 32)   // 50000 exact 32-edge chunks
#define NB      196            // scan blocks (196*256 >= 50001)
#define NT_NODE ((NN + 63) / 64)
#define EW      8              // waves per edge-kernel block (512 thr — >512 spills!)

typedef __attribute__((ext_vector_type(8))) short bf16x8;
typedef __attribute__((ext_vector_type(4))) float f32x4;
typedef unsigned short u16;
typedef unsigned int u32;

__device__ __forceinline__ u16 f2bf(float x) {
  return __builtin_bit_cast(u16, __float2bfloat16(x));   // RNE (prep paths)
}
__device__ __forceinline__ u32 pk2bf(float lo, float hi) {
  return (u32)f2bf(lo) | ((u32)f2bf(hi) << 16);
}
// fast truncating pack for activations (error < 1 ulp bf16, biased to zero;
// headroom: absmax 2.0 vs threshold 12.7)
__device__ __forceinline__ u32 pk2bf_t(float lo, float hi) {
  return (__builtin_bit_cast(u32, lo) >> 16) |
         (__builtin_bit_cast(u32, hi) & 0xFFFF0000u);
}
__device__ __forceinline__ u16 f2bf_t(float x) {
  return (u16)(__builtin_bit_cast(u32, x) >> 16);
}
__device__ __forceinline__ float silu_f(float x) { return x / (1.0f + __expf(-x)); }

__device__ __forceinline__ bf16x8 ldf8(const float* __restrict__ p) {
  float4 a = ((const float4*)p)[0];
  float4 b = ((const float4*)p)[1];
  bf16x8 r;
  r[0] = (short)f2bf(a.x); r[1] = (short)f2bf(a.y);
  r[2] = (short)f2bf(a.z); r[3] = (short)f2bf(a.w);
  r[4] = (short)f2bf(b.x); r[5] = (short)f2bf(b.y);
  r[6] = (short)f2bf(b.z); r[7] = (short)f2bf(b.w);
  return r;
}

struct Feats { bf16x8 s0a, s0b, s1a, s1b, d0a, d0b, d1a, d1b, e0, e1; };

__device__ __forceinline__ void load_feats(Feats& f, int use16,
    const u16* __restrict__ nf16, const float* __restrict__ nf,
    const float* __restrict__ ef,
    int s0, int s1, int d0, int d1, int e0i, int e1i, int g8)
{
  if (use16) {
    f.s0a = *(const bf16x8*)(nf16 + (size_t)s0*64 + g8);
    f.s0b = *(const bf16x8*)(nf16 + (size_t)s0*64 + 32 + g8);
    f.s1a = *(const bf16x8*)(nf16 + (size_t)s1*64 + g8);
    f.s1b = *(const bf16x8*)(nf16 + (size_t)s1*64 + 32 + g8);
    f.d0a = *(const bf16x8*)(nf16 + (size_t)d0*64 + g8);
    f.d0b = *(const bf16x8*)(nf16 + (size_t)d0*64 + 32 + g8);
    f.d1a = *(const bf16x8*)(nf16 + (size_t)d1*64 + g8);
    f.d1b = *(const bf16x8*)(nf16 + (size_t)d1*64 + 32 + g8);
  } else {
    f.s0a = ldf8(nf + (size_t)s0*64 + g8);
    f.s0b = ldf8(nf + (size_t)s0*64 + 32 + g8);
    f.s1a = ldf8(nf + (size_t)s1*64 + g8);
    f.s1b = ldf8(nf + (size_t)s1*64 + 32 + g8);
    f.d0a = ldf8(nf + (size_t)d0*64 + g8);
    f.d0b = ldf8(nf + (size_t)d0*64 + 32 + g8);
    f.d1a = ldf8(nf + (size_t)d1*64 + g8);
    f.d1b = ldf8(nf + (size_t)d1*64 + 32 + g8);
  }
  if (g8 < 16) {                      // edge_feat fp32 (64B rows = same granule)
    f.e0 = ldf8(ef + (size_t)e0i*16 + g8);
    f.e1 = ldf8(ef + (size_t)e1i*16 + g8);
  } else { f.e0 = (bf16x8){0,0,0,0,0,0,0,0}; f.e1 = f.e0; }
}

// ---------------------------------------------------------------------------
// Fused prep: node cvt + dst histogram + msg_tot zero + out_coord=coord.
// ---------------------------------------------------------------------------
__global__ void prep_k(const float* __restrict__ nf, u16* __restrict__ nf16,
                       const int* __restrict__ eidx, int* __restrict__ count,
                       float* __restrict__ msg_tot,
                       const float* __restrict__ coord, float* __restrict__ out_coord,
                       int use16) {
  const int tid = blockIdx.x * blockDim.x + threadIdx.x;
  const int stride = gridDim.x * blockDim.x;
  if (use16) {
    for (int i = tid; i < NN*64/4; i += stride) {
      float4 v = ((const float4*)nf)[i];
      uint2 p = { pk2bf(v.x, v.y), pk2bf(v.z, v.w) };
      ((uint2*)nf16)[i] = p;
    }
  }
  const float4 z4 = {0.f, 0.f, 0.f, 0.f};
  for (int i = tid; i < NN*64/4; i += stride) ((float4*)msg_tot)[i] = z4;
  for (int i = tid; i < NN*3; i += stride) out_coord[i] = coord[i];
  for (int i = tid; i < E_TOT; i += stride) atomicAdd(&count[eidx[E_TOT + i]], 1);
}

__global__ __launch_bounds__(256) void scanA_k(const int* __restrict__ count,
                                               int* __restrict__ bsum) {
  __shared__ int sm[256];
  int idx = blockIdx.x * 256 + threadIdx.x;
  sm[threadIdx.x] = (idx < NN) ? count[idx] : 0;
  __syncthreads();
  for (int off = 128; off > 0; off >>= 1) {
    if (threadIdx.x < off) sm[threadIdx.x] += sm[threadIdx.x + off];
    __syncthreads();
  }
  if (threadIdx.x == 0) bsum[blockIdx.x] = sm[0];
}

__global__ __launch_bounds__(256) void scanB_k(const int* __restrict__ bsum,
                                               int* __restrict__ boff) {
  __shared__ int sm[256];
  int t = threadIdx.x;
  int v = (t < NB) ? bsum[t] : 0;
  sm[t] = v; __syncthreads();
  for (int off = 1; off < 256; off <<= 1) {
    int x = (t >= off) ? sm[t - off] : 0;
    __syncthreads();
    sm[t] += x;
    __syncthreads();
  }
  boff[t] = sm[t] - v;                 // exclusive prefix of block sums
}

__global__ __launch_bounds__(256) void scanC_k(const int* __restrict__ count,
                                               const int* __restrict__ boff,
                                               int* __restrict__ cursor) {
  __shared__ int sm[256];
  int idx = blockIdx.x * 256 + threadIdx.x, t = threadIdx.x;
  int v = (idx < NN) ? count[idx] : 0;
  sm[t] = v; __syncthreads();
  for (int off = 1; off < 256; off <<= 1) {
    int x = (t >= off) ? sm[t - off] : 0;
    __syncthreads();
    sm[t] += x;
    __syncthreads();
  }
  if (idx < NN) cursor[idx] = boff[blockIdx.x] + sm[t] - v;
}

// scatter: write dst-sorted meta {src,dst,eid} only (rel/dist computed in
// edge kernel from L2-resident coord — 600KB, truly cache-fit)
__global__ void scatter_k(const int* __restrict__ eidx,
                          int* __restrict__ cursor,
                          int4* __restrict__ meta) {
  int i = blockIdx.x * blockDim.x + threadIdx.x;
  int stride = gridDim.x * blockDim.x;
  for (; i < E_TOT; i += stride) {
    int s = eidx[i];
    int d = eidx[E_TOT + i];
    int pos = atomicAdd(&cursor[d], 1);
    meta[pos] = make_int4(s, d, i, 0);
  }
}

// ---------------------------------------------------------------------------
// Edge kernel v14 (= round-12 best + geo-drop + fast activation packs).
// Weights in LDS (one barrier); coalesced meta; rel/dist from coord in the
// pipelined stage-2; packed epilogues (truncating bf16); coalesced 256B msg
// atomics via register transpose.
// B n-maps: GEMM1 n = 8*(lane&15)+nt ; GEMM2/3 n = 4*(lane&15)+nt.
// A/B k-map (shared): k = 32*kb + (lane>>4)*8 + j  (permutation-safe).
// C/D: hw-col = lane&15, row = (lane>>4)*4 + reg   (HW-verified).
// ---------------------------------------------------------------------------
__global__ __launch_bounds__(512, 2) void egnn_edge(
    const float* __restrict__ node_feat, const float* __restrict__ coord,
    const float* __restrict__ edge_feat, const int4* __restrict__ meta,
    const float* __restrict__ w1_msg, const float* __restrict__ w2_msg,
    const float* __restrict__ w1_mov, const float* __restrict__ w2_mov,
    const u16* __restrict__ nf16, int use16,
    float* __restrict__ msg_tot, float* __restrict__ out_coord)
{
  __shared__ u16 w1f[6*8*64*8];     // 48KB
  __shared__ u16 w2f[4*4*64*8];     // 16KB
  __shared__ u16 w3f[2*4*64*8];     // 8KB
  __shared__ u16 act[EW][32*HS2];   // 69.6KB (total 141.6KB)

  const int t = threadIdx.x;
  const int lane = t & 63;
  const int wv = t >> 6;              // 0..7
  const int cl = lane & 15;
  const int g8 = (lane >> 4) * 8;
  const int orow4 = (lane >> 4) * 4;
  const int el = lane & 31;

  for (int i = t; i < 6*8*64*8; i += 512) {
    int j = i & 7, l = (i >> 3) & 63, nt = (i >> 9) & 7, kb = i >> 12;
    int k = kb*32 + (l >> 4)*8 + j;
    w1f[i] = f2bf(k < K1 ? w1_msg[k*H1 + 8*(l & 15) + nt] : 0.0f);
  }
  for (int i = t; i < 4*4*64*8; i += 512) {
    int j = i & 7, l = (i >> 3) & 63, nt = (i >> 9) & 3, kb = i >> 11;
    w2f[i] = f2bf(w2_msg[(kb*32 + (l >> 4)*8 + j)*64 + 4*(l & 15) + nt]);
  }
  for (int i = t; i < 2*4*64*8; i += 512) {
    int j = i & 7, l = (i >> 3) & 63, nt = (i >> 9) & 3, kb = i >> 11;
    w3f[i] = f2bf(w1_mov[(kb*32 + (l >> 4)*8 + j)*64 + 4*(l & 15) + nt]);
  }
  float w2m_r[4];
  #pragma unroll
  for (int nt = 0; nt < 4; ++nt) w2m_r[nt] = w2_mov[4*cl + nt];

  __syncthreads();                    // weights ready; no barriers after this

  u16* const myact = &act[wv][0];
  const int NW = gridDim.x * EW;

  int g = blockIdx.x * EW + wv;
  if (g >= NGC) return;

  // ---- prologue: coalesced meta + coord gathers + feature gathers ----
  int4 mm = meta[g*32 + el];
  int dv = mm.y;
  float rx = coord[(size_t)mm.y*3+0] - coord[(size_t)mm.x*3+0];
  float ry = coord[(size_t)mm.y*3+1] - coord[(size_t)mm.x*3+1];
  float rz = coord[(size_t)mm.y*3+2] - coord[(size_t)mm.x*3+2];
  float dist = sqrtf(rx*rx + ry*ry + rz*rz);
  float dist0 = __shfl(dist, cl), dist1 = __shfl(dist, 16 + cl);
  Feats cf;
  {
    int s0 = __shfl(mm.x, cl), s1 = __shfl(mm.x, 16 + cl);
    int d0 = __shfl(mm.y, cl), d1 = __shfl(mm.y, 16 + cl);
    int e0i = __shfl(mm.z, cl), e1i = __shfl(mm.z, 16 + cl);
    load_feats(cf, use16, nf16, node_feat, edge_feat,
               s0, s1, d0, d1, e0i, e1i, g8);
  }

  while (true) {
    const int gn = g + NW;
    const bool hn = gn < NGC;

    // ---- stage 0: next chunk's meta (coalesced) ----
    int4 nm = make_int4(0,0,0,0);
    if (hn) nm = meta[gn*32 + el];

    // ---- rbf fragments (current chunk) ----
    bf16x8 rbf0, rbf1;
    #pragma unroll
    for (int j = 0; j < 8; ++j) {
      float c = (float)(g8 + j) * (10.0f / 31.0f);
      float u0 = dist0 - c, u1 = dist1 - c;
      rbf0[j] = (short)f2bf_t(__expf(-10.0f * u0 * u0));
      rbf1[j] = (short)f2bf_t(__expf(-10.0f * u1 * u1));
    }

    // ---- GEMM1: h = silu(m_in @ W1)  [32x192]@[192x128] ----
    f32x4 acc1[2][8];
    #pragma unroll
    for (int rt = 0; rt < 2; ++rt)
      #pragma unroll
      for (int nt = 0; nt < 8; ++nt) acc1[rt][nt] = (f32x4){0.f,0.f,0.f,0.f};
    #pragma unroll
    for (int kb = 0; kb < 6; ++kb) {
      bf16x8 af0, af1;
      if      (kb == 0) { af0 = cf.s0a; af1 = cf.s1a; }
      else if (kb == 1) { af0 = cf.s0b; af1 = cf.s1b; }
      else if (kb == 2) { af0 = cf.d0a; af1 = cf.d1a; }
      else if (kb == 3) { af0 = cf.d0b; af1 = cf.d1b; }
      else if (kb == 4) { af0 = rbf0;   af1 = rbf1;   }
      else              { af0 = cf.e0;  af1 = cf.e1;  }
      #pragma unroll
      for (int nt = 0; nt < 8; ++nt) {
        bf16x8 bw = *(const bf16x8*)(w1f + ((kb*8 + nt)*64 + lane)*8);
        acc1[0][nt] = __builtin_amdgcn_mfma_f32_16x16x32_bf16(af0, bw, acc1[0][nt], 0, 0, 0);
        acc1[1][nt] = __builtin_amdgcn_mfma_f32_16x16x32_bf16(af1, bw, acc1[1][nt], 0, 0, 0);
      }
    }
    // packed epilogue: lane holds h[row][8*cl .. 8*cl+7] for 8 rows
    #pragma unroll
    for (int rt = 0; rt < 2; ++rt)
      #pragma unroll
      for (int r = 0; r < 4; ++r) {
        uint4 q;
        q.x = pk2bf_t(silu_f(acc1[rt][0][r]), silu_f(acc1[rt][1][r]));
        q.y = pk2bf_t(silu_f(acc1[rt][2][r]), silu_f(acc1[rt][3][r]));
        q.z = pk2bf_t(silu_f(acc1[rt][4][r]), silu_f(acc1[rt][5][r]));
        q.w = pk2bf_t(silu_f(acc1[rt][6][r]), silu_f(acc1[rt][7][r]));
        *(uint4*)(myact + (rt*16 + orow4 + r)*HS2 + 8*cl) = q;
      }
    asm volatile("" ::: "memory");    // h-writes before h-reads (program order)

    // ---- GEMM2: msg = silu(h @ W2)  [32x128]@[128x64] ----
    f32x4 acc2[2][4];
    #pragma unroll
    for (int rt = 0; rt < 2; ++rt)
      #pragma unroll
      for (int nt = 0; nt < 4; ++nt) acc2[rt][nt] = (f32x4){0.f,0.f,0.f,0.f};
    #pragma unroll
    for (int kb = 0; kb < 4; ++kb) {
      bf16x8 a0 = *(const bf16x8*)(myact + cl*HS2 + kb*32 + g8);
      bf16x8 a1 = *(const bf16x8*)(myact + (16 + cl)*HS2 + kb*32 + g8);
      #pragma unroll
      for (int nt = 0; nt < 4; ++nt) {
        bf16x8 bw = *(const bf16x8*)(w2f + ((kb*4 + nt)*64 + lane)*8);
        acc2[0][nt] = __builtin_amdgcn_mfma_f32_16x16x32_bf16(a0, bw, acc2[0][nt], 0, 0, 0);
        acc2[1][nt] = __builtin_amdgcn_mfma_f32_16x16x32_bf16(a1, bw, acc2[1][nt], 0, 0, 0);
      }
    }
    asm volatile("" ::: "memory");
    // mval regs (col = 4*cl+nt) + packed m -> act cols 0..63
    float mval[2][4][4];
    #pragma unroll
    for (int rt = 0; rt < 2; ++rt)
      #pragma unroll
      for (int r = 0; r < 4; ++r) {
        #pragma unroll
        for (int nt = 0; nt < 4; ++nt) mval[rt][nt][r] = silu_f(acc2[rt][nt][r]);
        uint2 q;
        q.x = pk2bf_t(mval[rt][0][r], mval[rt][1][r]);
        q.y = pk2bf_t(mval[rt][2][r], mval[rt][3][r]);
        *(uint2*)(myact + (rt*16 + orow4 + r)*HS2 + 4*cl) = q;
      }
    asm volatile("" ::: "memory");    // m-writes before m-reads

    // ---- stage 2: next chunk's coord + feature gathers ----
    float nrx = 0.f, nry = 0.f, nrz = 0.f, ndist0 = 0.f, ndist1 = 0.f;
    Feats nf_;
    if (hn) {
      nrx = coord[(size_t)nm.y*3+0] - coord[(size_t)nm.x*3+0];
      nry = coord[(size_t)nm.y*3+1] - coord[(size_t)nm.x*3+1];
      nrz = coord[(size_t)nm.y*3+2] - coord[(size_t)nm.x*3+2];
      float nd = sqrtf(nrx*nrx + nry*nry + nrz*nrz);
      ndist0 = __shfl(nd, cl); ndist1 = __shfl(nd, 16 + cl);
      int s0 = __shfl(nm.x, cl), s1 = __shfl(nm.x, 16 + cl);
      int d0 = __shfl(nm.y, cl), d1 = __shfl(nm.y, 16 + cl);
      int e0i = __shfl(nm.z, cl), e1i = __shfl(nm.z, 16 + cl);
      load_feats(nf_, use16, nf16, node_feat, edge_feat,
                 s0, s1, d0, d1, e0i, e1i, g8);
    }

    // ---- GEMM3: s = silu(msg @ W3) @ w2_mov ----
    f32x4 acc3[2][4];
    #pragma unroll
    for (int rt = 0; rt < 2; ++rt)
      #pragma unroll
      for (int nt = 0; nt < 4; ++nt) acc3[rt][nt] = (f32x4){0.f,0.f,0.f,0.f};
    #pragma unroll
    for (int kb = 0; kb < 2; ++kb) {
      bf16x8 a0 = *(const bf16x8*)(myact + cl*HS2 + kb*32 + g8);
      bf16x8 a1 = *(const bf16x8*)(myact + (16 + cl)*HS2 + kb*32 + g8);
      #pragma unroll
      for (int nt = 0; nt < 4; ++nt) {
        bf16x8 bw = *(const bf16x8*)(w3f + ((kb*4 + nt)*64 + lane)*8);
        acc3[0][nt] = __builtin_amdgcn_mfma_f32_16x16x32_bf16(a0, bw, acc3[0][nt], 0, 0, 0);
        acc3[1][nt] = __builtin_amdgcn_mfma_f32_16x16x32_bf16(a1, bw, acc3[1][nt], 0, 0, 0);
      }
    }
    float prt[2][4];
    #pragma unroll
    for (int rt = 0; rt < 2; ++rt)
      #pragma unroll
      for (int r = 0; r < 4; ++r) prt[rt][r] = 0.f;
    #pragma unroll
    for (int nt = 0; nt < 4; ++nt)
      #pragma unroll
      for (int rt = 0; rt < 2; ++rt)
        #pragma unroll
        for (int r = 0; r < 4; ++r)
          prt[rt][r] += silu_f(acc3[rt][nt][r]) * w2m_r[nt];
    #pragma unroll
    for (int off = 1; off < 16; off <<= 1)
      #pragma unroll
      for (int rt = 0; rt < 2; ++rt)
        #pragma unroll
        for (int r = 0; r < 4; ++r) prt[rt][r] += __shfl_xor(prt[rt][r], off, 64);

    // per-row rel vectors (broadcast once)
    float rxv[2][4], ryv[2][4], rzv[2][4];
    #pragma unroll
    for (int rt = 0; rt < 2; ++rt)
      #pragma unroll
      for (int r = 0; r < 4; ++r) {
        int row = rt*16 + orow4 + r;
        rxv[rt][r] = __shfl(rx, row);
        ryv[rt][r] = __shfl(ry, row);
        rzv[rt][r] = __shfl(rz, row);
      }

    // ---- segmented aggregation over dst-runs (rows sorted by dst) ----
    int start = 0;
    while (start < 32) {
      int node = __shfl(dv, start);
      unsigned long long b = __ballot(dv == node);
      unsigned m32 = (unsigned)b;
      unsigned rest = ~m32 & (0xFFFFFFFFu << start);
      int end = rest ? (__ffs(rest) - 1) : 32;

      float msum[4] = {0.f, 0.f, 0.f, 0.f};
      float sx = 0.f, sy = 0.f, sz = 0.f;
      #pragma unroll
      for (int rt = 0; rt < 2; ++rt)
        #pragma unroll
        for (int r = 0; r < 4; ++r) {
          int row = rt*16 + orow4 + r;
          float mk = (row >= start && row < end) ? 1.0f : 0.0f;
          #pragma unroll
          for (int nt = 0; nt < 4; ++nt) msum[nt] += mval[rt][nt][r] * mk;
          float s = prt[rt][r] * mk;
          sx += rxv[rt][r] * s; sy += ryv[rt][r] * s; sz += rzv[rt][r] * s;
        }
      #pragma unroll
      for (int nt = 0; nt < 4; ++nt) {
        msum[nt] += __shfl_xor(msum[nt], 16, 64);
        msum[nt] += __shfl_xor(msum[nt], 32, 64);
      }
      sx += __shfl_xor(sx, 16, 64); sx += __shfl_xor(sx, 32, 64);
      sy += __shfl_xor(sy, 16, 64); sy += __shfl_xor(sy, 32, 64);
      sz += __shfl_xor(sz, 16, 64); sz += __shfl_xor(sz, 32, 64);

      // register transpose: lane l takes column l (src lane l>>2, elem l&3)
      float t0 = __shfl(msum[0], lane >> 2);
      float t1 = __shfl(msum[1], lane >> 2);
      float t2 = __shfl(msum[2], lane >> 2);
      float t3 = __shfl(msum[3], lane >> 2);
      int sel = lane & 3;
      float val = sel == 0 ? t0 : (sel == 1 ? t1 : (sel == 2 ? t2 : t3));
      atomicAdd(&msg_tot[(size_t)node*64 + lane], val);   // 256B coalesced

      if (lane == 0) {
        atomicAdd(&out_coord[(size_t)node*3 + 0], sx);
        atomicAdd(&out_coord[(size_t)node*3 + 1], sy);
        atomicAdd(&out_coord[(size_t)node*3 + 2], sz);
      }
      start = end;
    }

    if (!hn) break;
    // ---- rotate pipeline ----
    g = gn;
    dv = nm.y;
    rx = nrx; ry = nry; rz = nrz;
    dist0 = ndist0; dist1 = ndist1;
    cf = nf_;
  }
}

// ---------------------------------------------------------------------------
// Node kernel (persistent): new_feat = node_feat + silu([f|msg]@W1n+b1)@W2n+b2
// ---------------------------------------------------------------------------
__global__ __launch_bounds__(256, 1) void egnn_node(
    const float* __restrict__ node_feat, const float* __restrict__ msg_tot,
    const float* __restrict__ w1n, const float* __restrict__ b1n,
    const float* __restrict__ w2n, const float* __restrict__ b2n,
    float* __restrict__ out_feat)
{
  __shared__ u16 w1f[4*8*64*8];   // 32KB  (n = 8*(l&15)+nt)
  __shared__ u16 w2f[4*4*64*8];   // 16KB  (n = 4*(l&15)+nt)
  __shared__ u16 a_lds[64*HS2];
  __shared__ u16 h_lds[64*HS2];
  __shared__ float b1s[128];
  __shared__ float b2s[64];

  const int t = threadIdx.x, lane = t & 63, wv = t >> 6;
  const int cl = lane & 15;
  const int row16 = wv*16 + cl;
  const int g8 = (lane >> 4) * 8;
  const int orow = wv*16 + (lane >> 4)*4;

  for (int i = t; i < 4*8*64*8; i += 256) {
    int j = i & 7, l = (i >> 3) & 63, nt = (i >> 9) & 7, kb = i >> 12;
    w1f[i] = f2bf(w1n[(kb*32 + (l >> 4)*8 + j)*128 + 8*(l & 15) + nt]);
  }
  for (int i = t; i < 4*4*64*8; i += 256) {
    int j = i & 7, l = (i >> 3) & 63, nt = (i >> 9) & 3, kb = i >> 11;
    w2f[i] = f2bf(w2n[(kb*32 + (l >> 4)*8 + j)*64 + 4*(l & 15) + nt]);
  }
  if (t < 128) b1s[t] = b1n[t];
  if (t < 64)  b2s[t] = b2n[t];

  for (int tile = blockIdx.x; tile < NT_NODE; tile += gridDim.x) {
    const int n0 = tile * 64;
    __syncthreads();                    // protect a_lds/h_lds reuse
    {
      const int nd = t >> 2, q = t & 3;
      const int gn = n0 + nd;
      u16* arow = a_lds + nd*HS2;
      if (gn < NN) {
        const float4* pf = (const float4*)(node_feat + (size_t)gn*64 + q*16);
        float4 vf = pf[0], vf2 = pf[1], vf3 = pf[2], vf4 = pf[3];
        uint4 qa = { pk2bf_t(vf.x, vf.y),  pk2bf_t(vf.z, vf.w),
                     pk2bf_t(vf2.x, vf2.y), pk2bf_t(vf2.z, vf2.w) };
        uint4 qb = { pk2bf_t(vf3.x, vf3.y), pk2bf_t(vf3.z, vf3.w),
                     pk2bf_t(vf4.x, vf4.y), pk2bf_t(vf4.z, vf4.w) };
        *(uint4*)(arow + q*16) = qa;
        *(uint4*)(arow + q*16 + 8) = qb;
        const float4* pm = (const float4*)(msg_tot + (size_t)gn*64 + q*16);
        float4 vm = pm[0], vm2 = pm[1], vm3 = pm[2], vm4 = pm[3];
        uint4 qc = { pk2bf_t(vm.x, vm.y),  pk2bf_t(vm.z, vm.w),
                     pk2bf_t(vm2.x, vm2.y), pk2bf_t(vm2.z, vm2.w) };
        uint4 qd = { pk2bf_t(vm3.x, vm3.y), pk2bf_t(vm3.z, vm3.w),
                     pk2bf_t(vm4.x, vm4.y), pk2bf_t(vm4.z, vm4.w) };
        *(uint4*)(arow + 64 + q*16) = qc;
        *(uint4*)(arow + 64 + q*16 + 8) = qd;
      } else {
        uint4 z = {0,0,0,0};
        *(uint4*)(arow + q*16) = z;  *(uint4*)(arow + q*16 + 8) = z;
        *(uint4*)(arow + 64 + q*16) = z; *(uint4*)(arow + 64 + q*16 + 8) = z;
      }
    }
    __syncthreads();
    {
      f32x4 acc[8];
      #pragma unroll
      for (int nt = 0; nt < 8; ++nt) acc[nt] = (f32x4){0.f,0.f,0.f,0.f};
      #pragma unroll
      for (int kb = 0; kb < 4; ++kb) {
        bf16x8 af = *(const bf16x8*)(a_lds + row16*HS2 + kb*32 + g8);
        #pragma unroll
        for (int nt = 0; nt < 8; ++nt) {
          bf16x8 bfv = *(const bf16x8*)(w1f + ((kb*8 + nt)*64 + lane)*8);
          acc[nt] = __builtin_amdgcn_mfma_f32_16x16x32_bf16(af, bfv, acc[nt], 0, 0, 0);
        }
      }
      #pragma unroll
      for (int r = 0; r < 4; ++r) {
        uint4 q;
        q.x = pk2bf_t(silu_f(acc[0][r] + b1s[8*cl+0]), silu_f(acc[1][r] + b1s[8*cl+1]));
        q.y = pk2bf_t(silu_f(acc[2][r] + b1s[8*cl+2]), silu_f(acc[3][r] + b1s[8*cl+3]));
        q.z = pk2bf_t(silu_f(acc[4][r] + b1s[8*cl+4]), silu_f(acc[5][r] + b1s[8*cl+5]));
        q.w = pk2bf_t(silu_f(acc[6][r] + b1s[8*cl+6]), silu_f(acc[7][r] + b1s[8*cl+7]));
        *(uint4*)(h_lds + (orow + r)*HS2 + 8*cl) = q;
      }
    }
    __syncthreads();
    {
      f32x4 acc[4];
      #pragma unroll
      for (int nt = 0; nt < 4; ++nt) acc[nt] = (f32x4){0.f,0.f,0.f,0.f};
      #pragma unroll
      for (int kb = 0; kb < 4; ++kb) {
        bf16x8 af = *(const bf16x8*)(h_lds + row16*HS2 + kb*32 + g8);
        #pragma unroll
        for (int nt = 0; nt < 4; ++nt) {
          bf16x8 bfv = *(const bf16x8*)(w2f + ((kb*4 + nt)*64 + lane)*8);
          acc[nt] = __builtin_amdgcn_mfma_f32_16x16x32_bf16(af, bfv, acc[nt], 0, 0, 0);
        }
      }
      #pragma unroll
      for (int r = 0; r < 4; ++r) {
        int row = orow + r, gn = n0 + row;
        if (gn < NN) {
          float4 base = *(const float4*)(node_feat + (size_t)gn*64 + 4*cl);
          float4 o;
          o.x = acc[0][r] + b2s[4*cl+0] + base.x;
          o.y = acc[1][r] + b2s[4*cl+1] + base.y;
          o.z = acc[2][r] + b2s[4*cl+2] + base.z;
          o.w = acc[3][r] + b2s[4*cl+3] + base.w;
          *(float4*)(out_feat + (size_t)gn*64 + 4*cl) = o;
        }
      }
    }
  }
}

extern "C" void kernel_launch(void* const* d_in, const int* in_sizes, int n_in,
                              void* d_out, int out_size, void* d_ws, size_t ws_size,
                              hipStream_t stream) {
  (void)in_sizes; (void)n_in; (void)out_size;
  const float* node_feat = (const float*)d_in[0];
  const float* coord     = (const float*)d_in[1];
  const float* edge_feat = (const float*)d_in[2];
  const int*   eidx      = (const int*)d_in[3];
  const float* w1_msg    = (const float*)d_in[4];
  const float* w2_msg    = (const float*)d_in[5];
  const float* w1_mov    = (const float*)d_in[6];
  const float* w2_mov    = (const float*)d_in[7];
  const float* w1n       = (const float*)d_in[9];
  const float* b1n       = (const float*)d_in[10];
  const float* w2n       = (const float*)d_in[11];
  const float* b2n       = (const float*)d_in[12];

  float* out_feat  = (float*)d_out;
  float* out_coord = out_feat + (size_t)NN * 64;

  // workspace layout (all 16B aligned)
  int*    count   = (int*)d_ws;                          // 50048
  int*    cursor  = count + 50048;                       // 50048
  int*    bsum    = cursor + 50048;                      // 1024
  int*    boff    = bsum + 1024;                         // 1024
  float*  msg_tot = (float*)(boff + 1024);               // 3.2M floats (12.8MB)
  int4*   meta    = (int4*)(msg_tot + (size_t)NN*64);    // 1.6M int4 (25.6MB)
  u16*    nf16    = (u16*)(meta + E_TOT);                // 3.2M u16 (6.4MB)
  const size_t need16 = (size_t)((char*)(nf16 + (size_t)NN*64) - (char*)d_ws);
  const int use16 = ws_size >= need16 ? 1 : 0;

  hipMemsetAsync(count, 0, NN * sizeof(int), stream);
  prep_k<<<2048, 256, 0, stream>>>(node_feat, nf16, eidx, count,
                                   msg_tot, coord, out_coord, use16);
  scanA_k<<<NB, 256, 0, stream>>>(count, bsum);
  scanB_k<<<1, 256, 0, stream>>>(bsum, boff);
  scanC_k<<<NB, 256, 0, stream>>>(count, boff, cursor);
  scatter_k<<<2048, 256, 0, stream>>>(eidx, cursor, meta);
  egnn_edge<<<256, 512, 0, stream>>>(node_feat, coord, edge_feat, meta,
      w1_msg, w2_msg, w1_mov, w2_mov, nf16, use16, msg_tot, out_coord);
  egnn_node<<<256, 256, 0, stream>>>(node_feat, msg_tot,
      w1n, b1n, w2n, b2n, out_feat);
}

// Round 15
// 542.814 us; speedup vs baseline: 1.7715x; 1.0777x over previous
//
#include <hip/hip_runtime.h>
#include <hip/hip_bf16.h>

#define E_TOT   1600000
#define NN      50000
#define K1      176     // msg MLP input dim (2*64+32+16)
#define H1      128     // MSG_HID
#define HS2     136     // act row stride (ushorts), 272B, 16B aligned
#define NGC     (E_TOT / 32)   // 50000 exact 32-edge chunks
#define NB      196            // scan blocks (196*256 >= 50001)
#define NT_NODE ((NN + 63) / 64)
#define EW      8              // waves per edge-kernel block (512 thr — >512 spills!)

typedef __attribute__((ext_vector_type(8))) short bf16x8;
typedef __attribute__((ext_vector_type(4))) float f32x4;
typedef unsigned short u16;
typedef unsigned int u32;

__device__ __forceinline__ u16 f2bf(float x) {
  return __builtin_bit_cast(u16, __float2bfloat16(x));   // RNE (prep paths)
}
__device__ __forceinline__ u32 pk2bf(float lo, float hi) {
  return (u32)f2bf(lo) | ((u32)f2bf(hi) << 16);
}
// truncating packs for activations (error <1 ulp bf16; passed at absmax 4.0)
__device__ __forceinline__ u32 pk2bf_t(float lo, float hi) {
  return (__builtin_bit_cast(u32, lo) >> 16) |
         (__builtin_bit_cast(u32, hi) & 0xFFFF0000u);
}
__device__ __forceinline__ u16 f2bf_t(float x) {
  return (u16)(__builtin_bit_cast(u32, x) >> 16);
}
__device__ __forceinline__ float silu_f(float x) { return x / (1.0f + __expf(-x)); }

__device__ __forceinline__ bf16x8 ldf8(const float* __restrict__ p) {
  float4 a = ((const float4*)p)[0];
  float4 b = ((const float4*)p)[1];
  bf16x8 r;
  r[0] = (short)f2bf(a.x); r[1] = (short)f2bf(a.y);
  r[2] = (short)f2bf(a.z); r[3] = (short)f2bf(a.w);
  r[4] = (short)f2bf(b.x); r[5] = (short)f2bf(b.y);
  r[6] = (short)f2bf(b.z); r[7] = (short)f2bf(b.w);
  return r;
}

struct Feats { bf16x8 s0a, s0b, s1a, s1b, d0a, d0b, d1a, d1b, e0, e1; };

__device__ __forceinline__ void load_feats(Feats& f, int use16,
    const u16* __restrict__ nf16, const float* __restrict__ nf,
    const float* __restrict__ ef,
    int s0, int s1, int d0, int d1, int e0i, int e1i, int g8)
{
  if (use16) {
    f.s0a = *(const bf16x8*)(nf16 + (size_t)s0*64 + g8);
    f.s0b = *(const bf16x8*)(nf16 + (size_t)s0*64 + 32 + g8);
    f.s1a = *(const bf16x8*)(nf16 + (size_t)s1*64 + g8);
    f.s1b = *(const bf16x8*)(nf16 + (size_t)s1*64 + 32 + g8);
    f.d0a = *(const bf16x8*)(nf16 + (size_t)d0*64 + g8);
    f.d0b = *(const bf16x8*)(nf16 + (size_t)d0*64 + 32 + g8);
    f.d1a = *(const bf16x8*)(nf16 + (size_t)d1*64 + g8);
    f.d1b = *(const bf16x8*)(nf16 + (size_t)d1*64 + 32 + g8);
  } else {
    f.s0a = ldf8(nf + (size_t)s0*64 + g8);
    f.s0b = ldf8(nf + (size_t)s0*64 + 32 + g8);
    f.s1a = ldf8(nf + (size_t)s1*64 + g8);
    f.s1b = ldf8(nf + (size_t)s1*64 + 32 + g8);
    f.d0a = ldf8(nf + (size_t)d0*64 + g8);
    f.d0b = ldf8(nf + (size_t)d0*64 + 32 + g8);
    f.d1a = ldf8(nf + (size_t)d1*64 + g8);
    f.d1b = ldf8(nf + (size_t)d1*64 + 32 + g8);
  }
  if (g8 < 16) {                      // edge_feat fp32 (64B rows = same granule)
    f.e0 = ldf8(ef + (size_t)e0i*16 + g8);
    f.e1 = ldf8(ef + (size_t)e1i*16 + g8);
  } else { f.e0 = (bf16x8){0,0,0,0,0,0,0,0}; f.e1 = f.e0; }
}

// ---------------------------------------------------------------------------
// Fused prep: node cvt + dst histogram + msg_tot zero + out_coord=coord.
// ---------------------------------------------------------------------------
__global__ void prep_k(const float* __restrict__ nf, u16* __restrict__ nf16,
                       const int* __restrict__ eidx, int* __restrict__ count,
                       float* __restrict__ msg_tot,
                       const float* __restrict__ coord, float* __restrict__ out_coord,
                       int use16) {
  const int tid = blockIdx.x * blockDim.x + threadIdx.x;
  const int stride = gridDim.x * blockDim.x;
  if (use16) {
    for (int i = tid; i < NN*64/4; i += stride) {
      float4 v = ((const float4*)nf)[i];
      uint2 p = { pk2bf(v.x, v.y), pk2bf(v.z, v.w) };
      ((uint2*)nf16)[i] = p;
    }
  }
  const float4 z4 = {0.f, 0.f, 0.f, 0.f};
  for (int i = tid; i < NN*64/4; i += stride) ((float4*)msg_tot)[i] = z4;
  for (int i = tid; i < NN*3; i += stride) out_coord[i] = coord[i];
  for (int i = tid; i < E_TOT; i += stride) atomicAdd(&count[eidx[E_TOT + i]], 1);
}

__global__ __launch_bounds__(256) void scanA_k(const int* __restrict__ count,
                                               int* __restrict__ bsum) {
  __shared__ int sm[256];
  int idx = blockIdx.x * 256 + threadIdx.x;
  sm[threadIdx.x] = (idx < NN) ? count[idx] : 0;
  __syncthreads();
  for (int off = 128; off > 0; off >>= 1) {
    if (threadIdx.x < off) sm[threadIdx.x] += sm[threadIdx.x + off];
    __syncthreads();
  }
  if (threadIdx.x == 0) bsum[blockIdx.x] = sm[0];
}

// scanC (merged with former scanB): each block redoes the tiny block-sum
// prefix locally, then scans its own 256 counts.
__global__ __launch_bounds__(256) void scanC_k(const int* __restrict__ count,
                                               const int* __restrict__ bsum,
                                               int* __restrict__ cursor) {
  __shared__ int sb[256];
  __shared__ int sm[256];
  const int t = threadIdx.x;
  int vb = (t < NB) ? bsum[t] : 0;
  sb[t] = vb; __syncthreads();
  for (int off = 1; off < 256; off <<= 1) {
    int x = (t >= off) ? sb[t - off] : 0;
    __syncthreads();
    sb[t] += x;
    __syncthreads();
  }
  const int boff = sb[blockIdx.x] - bsum[blockIdx.x];   // exclusive prefix
  __syncthreads();
  int idx = blockIdx.x * 256 + t;
  int v = (idx < NN) ? count[idx] : 0;
  sm[t] = v; __syncthreads();
  for (int off = 1; off < 256; off <<= 1) {
    int x = (t >= off) ? sm[t - off] : 0;
    __syncthreads();
    sm[t] += x;
    __syncthreads();
  }
  if (idx < NN) cursor[idx] = boff + sm[t] - v;
}

// scatter: write dst-sorted meta {src,dst,eid} + geo {rel.xyz, dist}
__global__ void scatter_k(const int* __restrict__ eidx,
                          const float* __restrict__ coord,
                          int* __restrict__ cursor,
                          int4* __restrict__ meta, float4* __restrict__ geo) {
  int i = blockIdx.x * blockDim.x + threadIdx.x;
  int stride = gridDim.x * blockDim.x;
  for (; i < E_TOT; i += stride) {
    int s = eidx[i];
    int d = eidx[E_TOT + i];
    int pos = atomicAdd(&cursor[d], 1);
    float rx = coord[(size_t)d*3+0] - coord[(size_t)s*3+0];
    float ry = coord[(size_t)d*3+1] - coord[(size_t)s*3+1];
    float rz = coord[(size_t)d*3+2] - coord[(size_t)s*3+2];
    float dist = sqrtf(rx*rx + ry*ry + rz*rz);
    meta[pos] = make_int4(s, d, i, 0);
    geo[pos]  = make_float4(rx, ry, rz, dist);
  }
}

// ---------------------------------------------------------------------------
// Edge kernel v15 (= round-12 best + truncating activation packs).
// 512thr/(512,2) -> 128 VGPR no spill; weights in LDS; coalesced meta/geo
// streams; packed epilogues; coalesced 256B msg atomics (register transpose).
// B n-maps: GEMM1 n = 8*(lane&15)+nt ; GEMM2/3 n = 4*(lane&15)+nt.
// A/B k-map (shared): k = 32*kb + (lane>>4)*8 + j  (permutation-safe).
// C/D: hw-col = lane&15, row = (lane>>4)*4 + reg   (HW-verified).
// ---------------------------------------------------------------------------
__global__ __launch_bounds__(512, 2) void egnn_edge(
    const float* __restrict__ node_feat, const float* __restrict__ edge_feat,
    const int4* __restrict__ meta, const float4* __restrict__ geo,
    const float* __restrict__ w1_msg, const float* __restrict__ w2_msg,
    const float* __restrict__ w1_mov, const float* __restrict__ w2_mov,
    const u16* __restrict__ nf16, int use16,
    float* __restrict__ msg_tot, float* __restrict__ out_coord)
{
  __shared__ u16 w1f[6*8*64*8];     // 48KB
  __shared__ u16 w2f[4*4*64*8];     // 16KB
  __shared__ u16 w3f[2*4*64*8];     // 8KB
  __shared__ u16 act[EW][32*HS2];   // 69.6KB (total 141.6KB)

  const int t = threadIdx.x;
  const int lane = t & 63;
  const int wv = t >> 6;              // 0..7
  const int cl = lane & 15;
  const int g8 = (lane >> 4) * 8;
  const int orow4 = (lane >> 4) * 4;
  const int el = lane & 31;

  for (int i = t; i < 6*8*64*8; i += 512) {
    int j = i & 7, l = (i >> 3) & 63, nt = (i >> 9) & 7, kb = i >> 12;
    int k = kb*32 + (l >> 4)*8 + j;
    w1f[i] = f2bf(k < K1 ? w1_msg[k*H1 + 8*(l & 15) + nt] : 0.0f);
  }
  for (int i = t; i < 4*4*64*8; i += 512) {
    int j = i & 7, l = (i >> 3) & 63, nt = (i >> 9) & 3, kb = i >> 11;
    w2f[i] = f2bf(w2_msg[(kb*32 + (l >> 4)*8 + j)*64 + 4*(l & 15) + nt]);
  }
  for (int i = t; i < 2*4*64*8; i += 512) {
    int j = i & 7, l = (i >> 3) & 63, nt = (i >> 9) & 3, kb = i >> 11;
    w3f[i] = f2bf(w1_mov[(kb*32 + (l >> 4)*8 + j)*64 + 4*(l & 15) + nt]);
  }
  float w2m_r[4];
  #pragma unroll
  for (int nt = 0; nt < 4; ++nt) w2m_r[nt] = w2_mov[4*cl + nt];

  __syncthreads();                    // weights ready; no barriers after this

  u16* const myact = &act[wv][0];
  const int NW = gridDim.x * EW;

  int g = blockIdx.x * EW + wv;
  if (g >= NGC) return;

  // ---- prologue: coalesced meta/geo + feature gathers ----
  int4  mm = meta[g*32 + el];
  float4 qq = geo[g*32 + el];
  int dv = mm.y;
  float rx = qq.x, ry = qq.y, rz = qq.z;
  float dist0 = __shfl(qq.w, cl), dist1 = __shfl(qq.w, 16 + cl);
  Feats cf;
  {
    int s0 = __shfl(mm.x, cl), s1 = __shfl(mm.x, 16 + cl);
    int d0 = __shfl(mm.y, cl), d1 = __shfl(mm.y, 16 + cl);
    int e0i = __shfl(mm.z, cl), e1i = __shfl(mm.z, 16 + cl);
    load_feats(cf, use16, nf16, node_feat, edge_feat,
               s0, s1, d0, d1, e0i, e1i, g8);
  }

  while (true) {
    const int gn = g + NW;
    const bool hn = gn < NGC;

    // ---- stage 0: next chunk's meta/geo (coalesced, no chain) ----
    int4 nm = make_int4(0,0,0,0);
    float4 nq = make_float4(0.f,0.f,0.f,0.f);
    if (hn) { nm = meta[gn*32 + el]; nq = geo[gn*32 + el]; }

    // ---- rbf fragments (current chunk) ----
    bf16x8 rbf0, rbf1;
    #pragma unroll
    for (int j = 0; j < 8; ++j) {
      float c = (float)(g8 + j) * (10.0f / 31.0f);
      float u0 = dist0 - c, u1 = dist1 - c;
      rbf0[j] = (short)f2bf_t(__expf(-10.0f * u0 * u0));
      rbf1[j] = (short)f2bf_t(__expf(-10.0f * u1 * u1));
    }

    // ---- GEMM1: h = silu(m_in @ W1)  [32x192]@[192x128] ----
    f32x4 acc1[2][8];
    #pragma unroll
    for (int rt = 0; rt < 2; ++rt)
      #pragma unroll
      for (int nt = 0; nt < 8; ++nt) acc1[rt][nt] = (f32x4){0.f,0.f,0.f,0.f};
    #pragma unroll
    for (int kb = 0; kb < 6; ++kb) {
      bf16x8 af0, af1;
      if      (kb == 0) { af0 = cf.s0a; af1 = cf.s1a; }
      else if (kb == 1) { af0 = cf.s0b; af1 = cf.s1b; }
      else if (kb == 2) { af0 = cf.d0a; af1 = cf.d1a; }
      else if (kb == 3) { af0 = cf.d0b; af1 = cf.d1b; }
      else if (kb == 4) { af0 = rbf0;   af1 = rbf1;   }
      else              { af0 = cf.e0;  af1 = cf.e1;  }
      #pragma unroll
      for (int nt = 0; nt < 8; ++nt) {
        bf16x8 bw = *(const bf16x8*)(w1f + ((kb*8 + nt)*64 + lane)*8);
        acc1[0][nt] = __builtin_amdgcn_mfma_f32_16x16x32_bf16(af0, bw, acc1[0][nt], 0, 0, 0);
        acc1[1][nt] = __builtin_amdgcn_mfma_f32_16x16x32_bf16(af1, bw, acc1[1][nt], 0, 0, 0);
      }
    }
    // packed epilogue: lane holds h[row][8*cl .. 8*cl+7] for 8 rows
    #pragma unroll
    for (int rt = 0; rt < 2; ++rt)
      #pragma unroll
      for (int r = 0; r < 4; ++r) {
        uint4 q;
        q.x = pk2bf_t(silu_f(acc1[rt][0][r]), silu_f(acc1[rt][1][r]));
        q.y = pk2bf_t(silu_f(acc1[rt][2][r]), silu_f(acc1[rt][3][r]));
        q.z = pk2bf_t(silu_f(acc1[rt][4][r]), silu_f(acc1[rt][5][r]));
        q.w = pk2bf_t(silu_f(acc1[rt][6][r]), silu_f(acc1[rt][7][r]));
        *(uint4*)(myact + (rt*16 + orow4 + r)*HS2 + 8*cl) = q;
      }
    asm volatile("" ::: "memory");    // h-writes before h-reads (program order)

    // ---- GEMM2: msg = silu(h @ W2)  [32x128]@[128x64] ----
    f32x4 acc2[2][4];
    #pragma unroll
    for (int rt = 0; rt < 2; ++rt)
      #pragma unroll
      for (int nt = 0; nt < 4; ++nt) acc2[rt][nt] = (f32x4){0.f,0.f,0.f,0.f};
    #pragma unroll
    for (int kb = 0; kb < 4; ++kb) {
      bf16x8 a0 = *(const bf16x8*)(myact + cl*HS2 + kb*32 + g8);
      bf16x8 a1 = *(const bf16x8*)(myact + (16 + cl)*HS2 + kb*32 + g8);
      #pragma unroll
      for (int nt = 0; nt < 4; ++nt) {
        bf16x8 bw = *(const bf16x8*)(w2f + ((kb*4 + nt)*64 + lane)*8);
        acc2[0][nt] = __builtin_amdgcn_mfma_f32_16x16x32_bf16(a0, bw, acc2[0][nt], 0, 0, 0);
        acc2[1][nt] = __builtin_amdgcn_mfma_f32_16x16x32_bf16(a1, bw, acc2[1][nt], 0, 0, 0);
      }
    }
    asm volatile("" ::: "memory");
    // mval regs (col = 4*cl+nt) + packed m -> act cols 0..63
    float mval[2][4][4];
    #pragma unroll
    for (int rt = 0; rt < 2; ++rt)
      #pragma unroll
      for (int r = 0; r < 4; ++r) {
        #pragma unroll
        for (int nt = 0; nt < 4; ++nt) mval[rt][nt][r] = silu_f(acc2[rt][nt][r]);
        uint2 q;
        q.x = pk2bf_t(mval[rt][0][r], mval[rt][1][r]);
        q.y = pk2bf_t(mval[rt][2][r], mval[rt][3][r]);
        *(uint2*)(myact + (rt*16 + orow4 + r)*HS2 + 4*cl) = q;
      }
    asm volatile("" ::: "memory");    // m-writes before m-reads

    // ---- stage 2: next chunk's feature gathers ----
    Feats nf_;
    if (hn) {
      int s0 = __shfl(nm.x, cl), s1 = __shfl(nm.x, 16 + cl);
      int d0 = __shfl(nm.y, cl), d1 = __shfl(nm.y, 16 + cl);
      int e0i = __shfl(nm.z, cl), e1i = __shfl(nm.z, 16 + cl);
      load_feats(nf_, use16, nf16, node_feat, edge_feat,
                 s0, s1, d0, d1, e0i, e1i, g8);
    }

    // ---- GEMM3: s = silu(msg @ W3) @ w2_mov ----
    f32x4 acc3[2][4];
    #pragma unroll
    for (int rt = 0; rt < 2; ++rt)
      #pragma unroll
      for (int nt = 0; nt < 4; ++nt) acc3[rt][nt] = (f32x4){0.f,0.f,0.f,0.f};
    #pragma unroll
    for (int kb = 0; kb < 2; ++kb) {
      bf16x8 a0 = *(const bf16x8*)(myact + cl*HS2 + kb*32 + g8);
      bf16x8 a1 = *(const bf16x8*)(myact + (16 + cl)*HS2 + kb*32 + g8);
      #pragma unroll
      for (int nt = 0; nt < 4; ++nt) {
        bf16x8 bw = *(const bf16x8*)(w3f + ((kb*4 + nt)*64 + lane)*8);
        acc3[0][nt] = __builtin_amdgcn_mfma_f32_16x16x32_bf16(a0, bw, acc3[0][nt], 0, 0, 0);
        acc3[1][nt] = __builtin_amdgcn_mfma_f32_16x16x32_bf16(a1, bw, acc3[1][nt], 0, 0, 0);
      }
    }
    float prt[2][4];
    #pragma unroll
    for (int rt = 0; rt < 2; ++rt)
      #pragma unroll
      for (int r = 0; r < 4; ++r) prt[rt][r] = 0.f;
    #pragma unroll
    for (int nt = 0; nt < 4; ++nt)
      #pragma unroll
      for (int rt = 0; rt < 2; ++rt)
        #pragma unroll
        for (int r = 0; r < 4; ++r)
          prt[rt][r] += silu_f(acc3[rt][nt][r]) * w2m_r[nt];
    #pragma unroll
    for (int off = 1; off < 16; off <<= 1)
      #pragma unroll
      for (int rt = 0; rt < 2; ++rt)
        #pragma unroll
        for (int r = 0; r < 4; ++r) prt[rt][r] += __shfl_xor(prt[rt][r], off, 64);

    // per-row rel vectors (broadcast once)
    float rxv[2][4], ryv[2][4], rzv[2][4];
    #pragma unroll
    for (int rt = 0; rt < 2; ++rt)
      #pragma unroll
      for (int r = 0; r < 4; ++r) {
        int row = rt*16 + orow4 + r;
        rxv[rt][r] = __shfl(rx, row);
        ryv[rt][r] = __shfl(ry, row);
        rzv[rt][r] = __shfl(rz, row);
      }

    // ---- segmented aggregation over dst-runs (rows sorted by dst) ----
    int start = 0;
    while (start < 32) {
      int node = __shfl(dv, start);
      unsigned long long b = __ballot(dv == node);
      unsigned m32 = (unsigned)b;
      unsigned rest = ~m32 & (0xFFFFFFFFu << start);
      int end = rest ? (__ffs(rest) - 1) : 32;

      float msum[4] = {0.f, 0.f, 0.f, 0.f};
      float sx = 0.f, sy = 0.f, sz = 0.f;
      #pragma unroll
      for (int rt = 0; rt < 2; ++rt)
        #pragma unroll
        for (int r = 0; r < 4; ++r) {
          int row = rt*16 + orow4 + r;
          float mk = (row >= start && row < end) ? 1.0f : 0.0f;
          #pragma unroll
          for (int nt = 0; nt < 4; ++nt) msum[nt] += mval[rt][nt][r] * mk;
          float s = prt[rt][r] * mk;
          sx += rxv[rt][r] * s; sy += ryv[rt][r] * s; sz += rzv[rt][r] * s;
        }
      #pragma unroll
      for (int nt = 0; nt < 4; ++nt) {
        msum[nt] += __shfl_xor(msum[nt], 16, 64);
        msum[nt] += __shfl_xor(msum[nt], 32, 64);
      }
      sx += __shfl_xor(sx, 16, 64); sx += __shfl_xor(sx, 32, 64);
      sy += __shfl_xor(sy, 16, 64); sy += __shfl_xor(sy, 32, 64);
      sz += __shfl_xor(sz, 16, 64); sz += __shfl_xor(sz, 32, 64);

      // register transpose: lane l takes column l (src lane l>>2, elem l&3)
      float t0 = __shfl(msum[0], lane >> 2);
      float t1 = __shfl(msum[1], lane >> 2);
      float t2 = __shfl(msum[2], lane >> 2);
      float t3 = __shfl(msum[3], lane >> 2);
      int sel = lane & 3;
      float val = sel == 0 ? t0 : (sel == 1 ? t1 : (sel == 2 ? t2 : t3));
      atomicAdd(&msg_tot[(size_t)node*64 + lane], val);   // 256B coalesced

      if (lane == 0) {
        atomicAdd(&out_coord[(size_t)node*3 + 0], sx);
        atomicAdd(&out_coord[(size_t)node*3 + 1], sy);
        atomicAdd(&out_coord[(size_t)node*3 + 2], sz);
      }
      start = end;
    }

    if (!hn) break;
    // ---- rotate pipeline ----
    g = gn;
    dv = nm.y;
    rx = nq.x; ry = nq.y; rz = nq.z;
    dist0 = __shfl(nq.w, cl); dist1 = __shfl(nq.w, 16 + cl);
    cf = nf_;
  }
}

// ---------------------------------------------------------------------------
// Node kernel (persistent): new_feat = node_feat + silu([f|msg]@W1n+b1)@W2n+b2
// ---------------------------------------------------------------------------
__global__ __launch_bounds__(256, 1) void egnn_node(
    const float* __restrict__ node_feat, const float* __restrict__ msg_tot,
    const float* __restrict__ w1n, const float* __restrict__ b1n,
    const float* __restrict__ w2n, const float* __restrict__ b2n,
    float* __restrict__ out_feat)
{
  __shared__ u16 w1f[4*8*64*8];   // 32KB  (n = 8*(l&15)+nt)
  __shared__ u16 w2f[4*4*64*8];   // 16KB  (n = 4*(l&15)+nt)
  __shared__ u16 a_lds[64*HS2];
  __shared__ u16 h_lds[64*HS2];
  __shared__ float b1s[128];
  __shared__ float b2s[64];

  const int t = threadIdx.x, lane = t & 63, wv = t >> 6;
  const int cl = lane & 15;
  const int row16 = wv*16 + cl;
  const int g8 = (lane >> 4) * 8;
  const int orow = wv*16 + (lane >> 4)*4;

  for (int i = t; i < 4*8*64*8; i += 256) {
    int j = i & 7, l = (i >> 3) & 63, nt = (i >> 9) & 7, kb = i >> 12;
    w1f[i] = f2bf(w1n[(kb*32 + (l >> 4)*8 + j)*128 + 8*(l & 15) + nt]);
  }
  for (int i = t; i < 4*4*64*8; i += 256) {
    int j = i & 7, l = (i >> 3) & 63, nt = (i >> 9) & 3, kb = i >> 11;
    w2f[i] = f2bf(w2n[(kb*32 + (l >> 4)*8 + j)*64 + 4*(l & 15) + nt]);
  }
  if (t < 128) b1s[t] = b1n[t];
  if (t < 64)  b2s[t] = b2n[t];

  for (int tile = blockIdx.x; tile < NT_NODE; tile += gridDim.x) {
    const int n0 = tile * 64;
    __syncthreads();                    // protect a_lds/h_lds reuse
    {
      const int nd = t >> 2, q = t & 3;
      const int gn = n0 + nd;
      u16* arow = a_lds + nd*HS2;
      if (gn < NN) {
        const float4* pf = (const float4*)(node_feat + (size_t)gn*64 + q*16);
        float4 vf = pf[0], vf2 = pf[1], vf3 = pf[2], vf4 = pf[3];
        uint4 qa = { pk2bf_t(vf.x, vf.y),  pk2bf_t(vf.z, vf.w),
                     pk2bf_t(vf2.x, vf2.y), pk2bf_t(vf2.z, vf2.w) };
        uint4 qb = { pk2bf_t(vf3.x, vf3.y), pk2bf_t(vf3.z, vf3.w),
                     pk2bf_t(vf4.x, vf4.y), pk2bf_t(vf4.z, vf4.w) };
        *(uint4*)(arow + q*16) = qa;
        *(uint4*)(arow + q*16 + 8) = qb;
        const float4* pm = (const float4*)(msg_tot + (size_t)gn*64 + q*16);
        float4 vm = pm[0], vm2 = pm[1], vm3 = pm[2], vm4 = pm[3];
        uint4 qc = { pk2bf_t(vm.x, vm.y),  pk2bf_t(vm.z, vm.w),
                     pk2bf_t(vm2.x, vm2.y), pk2bf_t(vm2.z, vm2.w) };
        uint4 qd = { pk2bf_t(vm3.x, vm3.y), pk2bf_t(vm3.z, vm3.w),
                     pk2bf_t(vm4.x, vm4.y), pk2bf_t(vm4.z, vm4.w) };
        *(uint4*)(arow + 64 + q*16) = qc;
        *(uint4*)(arow + 64 + q*16 + 8) = qd;
      } else {
        uint4 z = {0,0,0,0};
        *(uint4*)(arow + q*16) = z;  *(uint4*)(arow + q*16 + 8) = z;
        *(uint4*)(arow + 64 + q*16) = z; *(uint4*)(arow + 64 + q*16 + 8) = z;
      }
    }
    __syncthreads();
    {
      f32x4 acc[8];
      #pragma unroll
      for (int nt = 0; nt < 8; ++nt) acc[nt] = (f32x4){0.f,0.f,0.f,0.f};
      #pragma unroll
      for (int kb = 0; kb < 4; ++kb) {
        bf16x8 af = *(const bf16x8*)(a_lds + row16*HS2 + kb*32 + g8);
        #pragma unroll
        for (int nt = 0; nt < 8; ++nt) {
          bf16x8 bfv = *(const bf16x8*)(w1f + ((kb*8 + nt)*64 + lane)*8);
          acc[nt] = __builtin_amdgcn_mfma_f32_16x16x32_bf16(af, bfv, acc[nt], 0, 0, 0);
        }
      }
      #pragma unroll
      for (int r = 0; r < 4; ++r) {
        uint4 q;
        q.x = pk2bf_t(silu_f(acc[0][r] + b1s[8*cl+0]), silu_f(acc[1][r] + b1s[8*cl+1]));
        q.y = pk2bf_t(silu_f(acc[2][r] + b1s[8*cl+2]), silu_f(acc[3][r] + b1s[8*cl+3]));
        q.z = pk2bf_t(silu_f(acc[4][r] + b1s[8*cl+4]), silu_f(acc[5][r] + b1s[8*cl+5]));
        q.w = pk2bf_t(silu_f(acc[6][r] + b1s[8*cl+6]), silu_f(acc[7][r] + b1s[8*cl+7]));
        *(uint4*)(h_lds + (orow + r)*HS2 + 8*cl) = q;
      }
    }
    __syncthreads();
    {
      f32x4 acc[4];
      #pragma unroll
      for (int nt = 0; nt < 4; ++nt) acc[nt] = (f32x4){0.f,0.f,0.f,0.f};
      #pragma unroll
      for (int kb = 0; kb < 4; ++kb) {
        bf16x8 af = *(const bf16x8*)(h_lds + row16*HS2 + kb*32 + g8);
        #pragma unroll
        for (int nt = 0; nt < 4; ++nt) {
          bf16x8 bfv = *(const bf16x8*)(w2f + ((kb*4 + nt)*64 + lane)*8);
          acc[nt] = __builtin_amdgcn_mfma_f32_16x16x32_bf16(af, bfv, acc[nt], 0, 0, 0);
        }
      }
      #pragma unroll
      for (int r = 0; r < 4; ++r) {
        int row = orow + r, gn = n0 + row;
        if (gn < NN) {
          float4 base = *(const float4*)(node_feat + (size_t)gn*64 + 4*cl);
          float4 o;
          o.x = acc[0][r] + b2s[4*cl+0] + base.x;
          o.y = acc[1][r] + b2s[4*cl+1] + base.y;
          o.z = acc[2][r] + b2s[4*cl+2] + base.z;
          o.w = acc[3][r] + b2s[4*cl+3] + base.w;
          *(float4*)(out_feat + (size_t)gn*64 + 4*cl) = o;
        }
      }
    }
  }
}

extern "C" void kernel_launch(void* const* d_in, const int* in_sizes, int n_in,
                              void* d_out, int out_size, void* d_ws, size_t ws_size,
                              hipStream_t stream) {
  (void)in_sizes; (void)n_in; (void)out_size;
  const float* node_feat = (const float*)d_in[0];
  const float* coord     = (const float*)d_in[1];
  const float* edge_feat = (const float*)d_in[2];
  const int*   eidx      = (const int*)d_in[3];
  const float* w1_msg    = (const float*)d_in[4];
  const float* w2_msg    = (const float*)d_in[5];
  const float* w1_mov    = (const float*)d_in[6];
  const float* w2_mov    = (const float*)d_in[7];
  const float* w1n       = (const float*)d_in[9];
  const float* b1n       = (const float*)d_in[10];
  const float* w2n       = (const float*)d_in[11];
  const float* b2n       = (const float*)d_in[12];

  float* out_feat  = (float*)d_out;
  float* out_coord = out_feat + (size_t)NN * 64;

  // workspace layout (all 16B aligned)
  int*    count   = (int*)d_ws;                          // 50048
  int*    cursor  = count + 50048;                       // 50048
  int*    bsum    = cursor + 50048;                      // 1024
  int*    boff    = bsum + 1024;                         // 1024 (unused pad)
  float*  msg_tot = (float*)(boff + 1024);               // 3.2M floats (12.8MB)
  int4*   meta    = (int4*)(msg_tot + (size_t)NN*64);    // 1.6M int4 (25.6MB)
  float4* geo     = (float4*)(meta + E_TOT);             // 1.6M float4 (25.6MB)
  u16*    nf16    = (u16*)(geo + E_TOT);                 // 3.2M u16 (6.4MB)
  const size_t need16 = (size_t)((char*)(nf16 + (size_t)NN*64) - (char*)d_ws);
  const int use16 = ws_size >= need16 ? 1 : 0;

  hipMemsetAsync(count, 0, NN * sizeof(int), stream);
  prep_k<<<2048, 256, 0, stream>>>(node_feat, nf16, eidx, count,
                                   msg_tot, coord, out_coord, use16);
  scanA_k<<<NB, 256, 0, stream>>>(count, bsum);
  scanC_k<<<NB, 256, 0, stream>>>(count, bsum, cursor);
  scatter_k<<<2048, 256, 0, stream>>>(eidx, coord, cursor, meta, geo);
  egnn_edge<<<256, 512, 0, stream>>>(node_feat, edge_feat, meta, geo,
      w1_msg, w2_msg, w1_mov, w2_mov, nf16, use16, msg_tot, out_coord);
  egnn_node<<<256, 256, 0, stream>>>(node_feat, msg_tot,
      w1n, b1n, w2n, b2n, out_feat);
}

// Round 16
// 490.138 us; speedup vs baseline: 1.9618x; 1.1075x over previous
//
#include <hip/hip_runtime.h>
#include <hip/hip_bf16.h>

#define E_TOT   1600000
#define NN      50000
#define K1      176     // msg MLP input dim (2*64+32+16)
#define H1      128     // MSG_HID
#define HS2     136     // act row stride (ushorts), 272B, 16B aligned
#define NGC     (E_TOT / 32)   // 50000 exact 32-edge chunks
#define NB      196            // scan blocks (196*256 >= 50001)
#define NT_NODE ((NN + 63) / 64)
#define EW      8              // waves per edge-kernel block (512 thr — >512 spills!)

typedef __attribute__((ext_vector_type(8))) short bf16x8;
typedef __attribute__((ext_vector_type(4))) float f32x4;
typedef unsigned short u16;
typedef unsigned int u32;

__device__ __forceinline__ u16 f2bf(float x) {
  return __builtin_bit_cast(u16, __float2bfloat16(x));   // RNE (prep paths)
}
__device__ __forceinline__ u32 pk2bf(float lo, float hi) {
  return (u32)f2bf(lo) | ((u32)f2bf(hi) << 16);
}
// truncating packs for activations (error <1 ulp bf16; passed at absmax 4.0)
__device__ __forceinline__ u32 pk2bf_t(float lo, float hi) {
  return (__builtin_bit_cast(u32, lo) >> 16) |
         (__builtin_bit_cast(u32, hi) & 0xFFFF0000u);
}
__device__ __forceinline__ u16 f2bf_t(float x) {
  return (u16)(__builtin_bit_cast(u32, x) >> 16);
}
// fast silu: v_rcp_f32 instead of the IEEE div sequence (~8 fewer VALU ops).
// rcp is ~1ulp accurate — far below bf16 output precision.
__device__ __forceinline__ float silu_f(float x) {
  return x * __builtin_amdgcn_rcpf(1.0f + __expf(-x));
}

__device__ __forceinline__ bf16x8 ldf8(const float* __restrict__ p) {
  float4 a = ((const float4*)p)[0];
  float4 b = ((const float4*)p)[1];
  bf16x8 r;
  r[0] = (short)f2bf(a.x); r[1] = (short)f2bf(a.y);
  r[2] = (short)f2bf(a.z); r[3] = (short)f2bf(a.w);
  r[4] = (short)f2bf(b.x); r[5] = (short)f2bf(b.y);
  r[6] = (short)f2bf(b.z); r[7] = (short)f2bf(b.w);
  return r;
}

struct Feats { bf16x8 s0a, s0b, s1a, s1b, d0a, d0b, d1a, d1b, e0, e1; };

__device__ __forceinline__ void load_feats(Feats& f, int use16,
    const u16* __restrict__ nf16, const float* __restrict__ nf,
    const float* __restrict__ ef,
    int s0, int s1, int d0, int d1, int e0i, int e1i, int g8)
{
  if (use16) {
    f.s0a = *(const bf16x8*)(nf16 + (size_t)s0*64 + g8);
    f.s0b = *(const bf16x8*)(nf16 + (size_t)s0*64 + 32 + g8);
    f.s1a = *(const bf16x8*)(nf16 + (size_t)s1*64 + g8);
    f.s1b = *(const bf16x8*)(nf16 + (size_t)s1*64 + 32 + g8);
    f.d0a = *(const bf16x8*)(nf16 + (size_t)d0*64 + g8);
    f.d0b = *(const bf16x8*)(nf16 + (size_t)d0*64 + 32 + g8);
    f.d1a = *(const bf16x8*)(nf16 + (size_t)d1*64 + g8);
    f.d1b = *(const bf16x8*)(nf16 + (size_t)d1*64 + 32 + g8);
  } else {
    f.s0a = ldf8(nf + (size_t)s0*64 + g8);
    f.s0b = ldf8(nf + (size_t)s0*64 + 32 + g8);
    f.s1a = ldf8(nf + (size_t)s1*64 + g8);
    f.s1b = ldf8(nf + (size_t)s1*64 + 32 + g8);
    f.d0a = ldf8(nf + (size_t)d0*64 + g8);
    f.d0b = ldf8(nf + (size_t)d0*64 + 32 + g8);
    f.d1a = ldf8(nf + (size_t)d1*64 + g8);
    f.d1b = ldf8(nf + (size_t)d1*64 + 32 + g8);
  }
  if (g8 < 16) {                      // edge_feat fp32 (64B rows = same granule)
    f.e0 = ldf8(ef + (size_t)e0i*16 + g8);
    f.e1 = ldf8(ef + (size_t)e1i*16 + g8);
  } else { f.e0 = (bf16x8){0,0,0,0,0,0,0,0}; f.e1 = f.e0; }
}

// ---------------------------------------------------------------------------
// Fused prep: node cvt + dst histogram + msg_tot zero + out_coord=coord.
// ---------------------------------------------------------------------------
__global__ void prep_k(const float* __restrict__ nf, u16* __restrict__ nf16,
                       const int* __restrict__ eidx, int* __restrict__ count,
                       float* __restrict__ msg_tot,
                       const float* __restrict__ coord, float* __restrict__ out_coord,
                       int use16) {
  const int tid = blockIdx.x * blockDim.x + threadIdx.x;
  const int stride = gridDim.x * blockDim.x;
  if (use16) {
    for (int i = tid; i < NN*64/4; i += stride) {
      float4 v = ((const float4*)nf)[i];
      uint2 p = { pk2bf(v.x, v.y), pk2bf(v.z, v.w) };
      ((uint2*)nf16)[i] = p;
    }
  }
  const float4 z4 = {0.f, 0.f, 0.f, 0.f};
  for (int i = tid; i < NN*64/4; i += stride) ((float4*)msg_tot)[i] = z4;
  for (int i = tid; i < NN*3; i += stride) out_coord[i] = coord[i];
  for (int i = tid; i < E_TOT; i += stride) atomicAdd(&count[eidx[E_TOT + i]], 1);
}

__global__ __launch_bounds__(256) void scanA_k(const int* __restrict__ count,
                                               int* __restrict__ bsum) {
  __shared__ int sm[256];
  int idx = blockIdx.x * 256 + threadIdx.x;
  sm[threadIdx.x] = (idx < NN) ? count[idx] : 0;
  __syncthreads();
  for (int off = 128; off > 0; off >>= 1) {
    if (threadIdx.x < off) sm[threadIdx.x] += sm[threadIdx.x + off];
    __syncthreads();
  }
  if (threadIdx.x == 0) bsum[blockIdx.x] = sm[0];
}

// scanC (merged with former scanB): each block redoes the tiny block-sum
// prefix locally, then scans its own 256 counts.
__global__ __launch_bounds__(256) void scanC_k(const int* __restrict__ count,
                                               const int* __restrict__ bsum,
                                               int* __restrict__ cursor) {
  __shared__ int sb[256];
  __shared__ int sm[256];
  const int t = threadIdx.x;
  int vb = (t < NB) ? bsum[t] : 0;
  sb[t] = vb; __syncthreads();
  for (int off = 1; off < 256; off <<= 1) {
    int x = (t >= off) ? sb[t - off] : 0;
    __syncthreads();
    sb[t] += x;
    __syncthreads();
  }
  const int boff = sb[blockIdx.x] - bsum[blockIdx.x];   // exclusive prefix
  __syncthreads();
  int idx = blockIdx.x * 256 + t;
  int v = (idx < NN) ? count[idx] : 0;
  sm[t] = v; __syncthreads();
  for (int off = 1; off < 256; off <<= 1) {
    int x = (t >= off) ? sm[t - off] : 0;
    __syncthreads();
    sm[t] += x;
    __syncthreads();
  }
  if (idx < NN) cursor[idx] = boff + sm[t] - v;
}

// scatter: write dst-sorted meta {src,dst,eid} + geo {rel.xyz, dist}
__global__ void scatter_k(const int* __restrict__ eidx,
                          const float* __restrict__ coord,
                          int* __restrict__ cursor,
                          int4* __restrict__ meta, float4* __restrict__ geo) {
  int i = blockIdx.x * blockDim.x + threadIdx.x;
  int stride = gridDim.x * blockDim.x;
  for (; i < E_TOT; i += stride) {
    int s = eidx[i];
    int d = eidx[E_TOT + i];
    int pos = atomicAdd(&cursor[d], 1);
    float rx = coord[(size_t)d*3+0] - coord[(size_t)s*3+0];
    float ry = coord[(size_t)d*3+1] - coord[(size_t)s*3+1];
    float rz = coord[(size_t)d*3+2] - coord[(size_t)s*3+2];
    float dist = sqrtf(rx*rx + ry*ry + rz*rz);
    meta[pos] = make_int4(s, d, i, 0);
    geo[pos]  = make_float4(rx, ry, rz, dist);
  }
}

// ---------------------------------------------------------------------------
// Edge kernel v16 (= round-15 + fast-rcp silu).
// 512thr/(512,2) -> 128 VGPR no spill; weights in LDS; coalesced meta/geo
// streams; packed epilogues; coalesced 256B msg atomics (register transpose).
// B n-maps: GEMM1 n = 8*(lane&15)+nt ; GEMM2/3 n = 4*(lane&15)+nt.
// A/B k-map (shared): k = 32*kb + (lane>>4)*8 + j  (permutation-safe).
// C/D: hw-col = lane&15, row = (lane>>4)*4 + reg   (HW-verified).
// ---------------------------------------------------------------------------
__global__ __launch_bounds__(512, 2) void egnn_edge(
    const float* __restrict__ node_feat, const float* __restrict__ edge_feat,
    const int4* __restrict__ meta, const float4* __restrict__ geo,
    const float* __restrict__ w1_msg, const float* __restrict__ w2_msg,
    const float* __restrict__ w1_mov, const float* __restrict__ w2_mov,
    const u16* __restrict__ nf16, int use16,
    float* __restrict__ msg_tot, float* __restrict__ out_coord)
{
  __shared__ u16 w1f[6*8*64*8];     // 48KB
  __shared__ u16 w2f[4*4*64*8];     // 16KB
  __shared__ u16 w3f[2*4*64*8];     // 8KB
  __shared__ u16 act[EW][32*HS2];   // 69.6KB (total 141.6KB)

  const int t = threadIdx.x;
  const int lane = t & 63;
  const int wv = t >> 6;              // 0..7
  const int cl = lane & 15;
  const int g8 = (lane >> 4) * 8;
  const int orow4 = (lane >> 4) * 4;
  const int el = lane & 31;

  for (int i = t; i < 6*8*64*8; i += 512) {
    int j = i & 7, l = (i >> 3) & 63, nt = (i >> 9) & 7, kb = i >> 12;
    int k = kb*32 + (l >> 4)*8 + j;
    w1f[i] = f2bf(k < K1 ? w1_msg[k*H1 + 8*(l & 15) + nt] : 0.0f);
  }
  for (int i = t; i < 4*4*64*8; i += 512) {
    int j = i & 7, l = (i >> 3) & 63, nt = (i >> 9) & 3, kb = i >> 11;
    w2f[i] = f2bf(w2_msg[(kb*32 + (l >> 4)*8 + j)*64 + 4*(l & 15) + nt]);
  }
  for (int i = t; i < 2*4*64*8; i += 512) {
    int j = i & 7, l = (i >> 3) & 63, nt = (i >> 9) & 3, kb = i >> 11;
    w3f[i] = f2bf(w1_mov[(kb*32 + (l >> 4)*8 + j)*64 + 4*(l & 15) + nt]);
  }
  float w2m_r[4];
  #pragma unroll
  for (int nt = 0; nt < 4; ++nt) w2m_r[nt] = w2_mov[4*cl + nt];

  __syncthreads();                    // weights ready; no barriers after this

  u16* const myact = &act[wv][0];
  const int NW = gridDim.x * EW;

  int g = blockIdx.x * EW + wv;
  if (g >= NGC) return;

  // ---- prologue: coalesced meta/geo + feature gathers ----
  int4  mm = meta[g*32 + el];
  float4 qq = geo[g*32 + el];
  int dv = mm.y;
  float rx = qq.x, ry = qq.y, rz = qq.z;
  float dist0 = __shfl(qq.w, cl), dist1 = __shfl(qq.w, 16 + cl);
  Feats cf;
  {
    int s0 = __shfl(mm.x, cl), s1 = __shfl(mm.x, 16 + cl);
    int d0 = __shfl(mm.y, cl), d1 = __shfl(mm.y, 16 + cl);
    int e0i = __shfl(mm.z, cl), e1i = __shfl(mm.z, 16 + cl);
    load_feats(cf, use16, nf16, node_feat, edge_feat,
               s0, s1, d0, d1, e0i, e1i, g8);
  }

  while (true) {
    const int gn = g + NW;
    const bool hn = gn < NGC;

    // ---- stage 0: next chunk's meta/geo (coalesced, no chain) ----
    int4 nm = make_int4(0,0,0,0);
    float4 nq = make_float4(0.f,0.f,0.f,0.f);
    if (hn) { nm = meta[gn*32 + el]; nq = geo[gn*32 + el]; }

    // ---- rbf fragments (current chunk) ----
    bf16x8 rbf0, rbf1;
    #pragma unroll
    for (int j = 0; j < 8; ++j) {
      float c = (float)(g8 + j) * (10.0f / 31.0f);
      float u0 = dist0 - c, u1 = dist1 - c;
      rbf0[j] = (short)f2bf_t(__expf(-10.0f * u0 * u0));
      rbf1[j] = (short)f2bf_t(__expf(-10.0f * u1 * u1));
    }

    // ---- GEMM1: h = silu(m_in @ W1)  [32x192]@[192x128] ----
    f32x4 acc1[2][8];
    #pragma unroll
    for (int rt = 0; rt < 2; ++rt)
      #pragma unroll
      for (int nt = 0; nt < 8; ++nt) acc1[rt][nt] = (f32x4){0.f,0.f,0.f,0.f};
    #pragma unroll
    for (int kb = 0; kb < 6; ++kb) {
      bf16x8 af0, af1;
      if      (kb == 0) { af0 = cf.s0a; af1 = cf.s1a; }
      else if (kb == 1) { af0 = cf.s0b; af1 = cf.s1b; }
      else if (kb == 2) { af0 = cf.d0a; af1 = cf.d1a; }
      else if (kb == 3) { af0 = cf.d0b; af1 = cf.d1b; }
      else if (kb == 4) { af0 = rbf0;   af1 = rbf1;   }
      else              { af0 = cf.e0;  af1 = cf.e1;  }
      #pragma unroll
      for (int nt = 0; nt < 8; ++nt) {
        bf16x8 bw = *(const bf16x8*)(w1f + ((kb*8 + nt)*64 + lane)*8);
        acc1[0][nt] = __builtin_amdgcn_mfma_f32_16x16x32_bf16(af0, bw, acc1[0][nt], 0, 0, 0);
        acc1[1][nt] = __builtin_amdgcn_mfma_f32_16x16x32_bf16(af1, bw, acc1[1][nt], 0, 0, 0);
      }
    }
    // packed epilogue: lane holds h[row][8*cl .. 8*cl+7] for 8 rows
    #pragma unroll
    for (int rt = 0; rt < 2; ++rt)
      #pragma unroll
      for (int r = 0; r < 4; ++r) {
        uint4 q;
        q.x = pk2bf_t(silu_f(acc1[rt][0][r]), silu_f(acc1[rt][1][r]));
        q.y = pk2bf_t(silu_f(acc1[rt][2][r]), silu_f(acc1[rt][3][r]));
        q.z = pk2bf_t(silu_f(acc1[rt][4][r]), silu_f(acc1[rt][5][r]));
        q.w = pk2bf_t(silu_f(acc1[rt][6][r]), silu_f(acc1[rt][7][r]));
        *(uint4*)(myact + (rt*16 + orow4 + r)*HS2 + 8*cl) = q;
      }
    asm volatile("" ::: "memory");    // h-writes before h-reads (program order)

    // ---- GEMM2: msg = silu(h @ W2)  [32x128]@[128x64] ----
    f32x4 acc2[2][4];
    #pragma unroll
    for (int rt = 0; rt < 2; ++rt)
      #pragma unroll
      for (int nt = 0; nt < 4; ++nt) acc2[rt][nt] = (f32x4){0.f,0.f,0.f,0.f};
    #pragma unroll
    for (int kb = 0; kb < 4; ++kb) {
      bf16x8 a0 = *(const bf16x8*)(myact + cl*HS2 + kb*32 + g8);
      bf16x8 a1 = *(const bf16x8*)(myact + (16 + cl)*HS2 + kb*32 + g8);
      #pragma unroll
      for (int nt = 0; nt < 4; ++nt) {
        bf16x8 bw = *(const bf16x8*)(w2f + ((kb*4 + nt)*64 + lane)*8);
        acc2[0][nt] = __builtin_amdgcn_mfma_f32_16x16x32_bf16(a0, bw, acc2[0][nt], 0, 0, 0);
        acc2[1][nt] = __builtin_amdgcn_mfma_f32_16x16x32_bf16(a1, bw, acc2[1][nt], 0, 0, 0);
      }
    }
    asm volatile("" ::: "memory");
    // mval regs (col = 4*cl+nt) + packed m -> act cols 0..63
    float mval[2][4][4];
    #pragma unroll
    for (int rt = 0; rt < 2; ++rt)
      #pragma unroll
      for (int r = 0; r < 4; ++r) {
        #pragma unroll
        for (int nt = 0; nt < 4; ++nt) mval[rt][nt][r] = silu_f(acc2[rt][nt][r]);
        uint2 q;
        q.x = pk2bf_t(mval[rt][0][r], mval[rt][1][r]);
        q.y = pk2bf_t(mval[rt][2][r], mval[rt][3][r]);
        *(uint2*)(myact + (rt*16 + orow4 + r)*HS2 + 4*cl) = q;
      }
    asm volatile("" ::: "memory");    // m-writes before m-reads

    // ---- stage 2: next chunk's feature gathers ----
    Feats nf_;
    if (hn) {
      int s0 = __shfl(nm.x, cl), s1 = __shfl(nm.x, 16 + cl);
      int d0 = __shfl(nm.y, cl), d1 = __shfl(nm.y, 16 + cl);
      int e0i = __shfl(nm.z, cl), e1i = __shfl(nm.z, 16 + cl);
      load_feats(nf_, use16, nf16, node_feat, edge_feat,
                 s0, s1, d0, d1, e0i, e1i, g8);
    }

    // ---- GEMM3: s = silu(msg @ W3) @ w2_mov ----
    f32x4 acc3[2][4];
    #pragma unroll
    for (int rt = 0; rt < 2; ++rt)
      #pragma unroll
      for (int nt = 0; nt < 4; ++nt) acc3[rt][nt] = (f32x4){0.f,0.f,0.f,0.f};
    #pragma unroll
    for (int kb = 0; kb < 2; ++kb) {
      bf16x8 a0 = *(const bf16x8*)(myact + cl*HS2 + kb*32 + g8);
      bf16x8 a1 = *(const bf16x8*)(myact + (16 + cl)*HS2 + kb*32 + g8);
      #pragma unroll
      for (int nt = 0; nt < 4; ++nt) {
        bf16x8 bw = *(const bf16x8*)(w3f + ((kb*4 + nt)*64 + lane)*8);
        acc3[0][nt] = __builtin_amdgcn_mfma_f32_16x16x32_bf16(a0, bw, acc3[0][nt], 0, 0, 0);
        acc3[1][nt] = __builtin_amdgcn_mfma_f32_16x16x32_bf16(a1, bw, acc3[1][nt], 0, 0, 0);
      }
    }
    float prt[2][4];
    #pragma unroll
    for (int rt = 0; rt < 2; ++rt)
      #pragma unroll
      for (int r = 0; r < 4; ++r) prt[rt][r] = 0.f;
    #pragma unroll
    for (int nt = 0; nt < 4; ++nt)
      #pragma unroll
      for (int rt = 0; rt < 2; ++rt)
        #pragma unroll
        for (int r = 0; r < 4; ++r)
          prt[rt][r] += silu_f(acc3[rt][nt][r]) * w2m_r[nt];
    #pragma unroll
    for (int off = 1; off < 16; off <<= 1)
      #pragma unroll
      for (int rt = 0; rt < 2; ++rt)
        #pragma unroll
        for (int r = 0; r < 4; ++r) prt[rt][r] += __shfl_xor(prt[rt][r], off, 64);

    // per-row rel vectors (broadcast once)
    float rxv[2][4], ryv[2][4], rzv[2][4];
    #pragma unroll
    for (int rt = 0; rt < 2; ++rt)
      #pragma unroll
      for (int r = 0; r < 4; ++r) {
        int row = rt*16 + orow4 + r;
        rxv[rt][r] = __shfl(rx, row);
        ryv[rt][r] = __shfl(ry, row);
        rzv[rt][r] = __shfl(rz, row);
      }

    // ---- segmented aggregation over dst-runs (rows sorted by dst) ----
    int start = 0;
    while (start < 32) {
      int node = __shfl(dv, start);
      unsigned long long b = __ballot(dv == node);
      unsigned m32 = (unsigned)b;
      unsigned rest = ~m32 & (0xFFFFFFFFu << start);
      int end = rest ? (__ffs(rest) - 1) : 32;

      float msum[4] = {0.f, 0.f, 0.f, 0.f};
      float sx = 0.f, sy = 0.f, sz = 0.f;
      #pragma unroll
      for (int rt = 0; rt < 2; ++rt)
        #pragma unroll
        for (int r = 0; r < 4; ++r) {
          int row = rt*16 + orow4 + r;
          float mk = (row >= start && row < end) ? 1.0f : 0.0f;
          #pragma unroll
          for (int nt = 0; nt < 4; ++nt) msum[nt] += mval[rt][nt][r] * mk;
          float s = prt[rt][r] * mk;
          sx += rxv[rt][r] * s; sy += ryv[rt][r] * s; sz += rzv[rt][r] * s;
        }
      #pragma unroll
      for (int nt = 0; nt < 4; ++nt) {
        msum[nt] += __shfl_xor(msum[nt], 16, 64);
        msum[nt] += __shfl_xor(msum[nt], 32, 64);
      }
      sx += __shfl_xor(sx, 16, 64); sx += __shfl_xor(sx, 32, 64);
      sy += __shfl_xor(sy, 16, 64); sy += __shfl_xor(sy, 32, 64);
      sz += __shfl_xor(sz, 16, 64); sz += __shfl_xor(sz, 32, 64);

      // register transpose: lane l takes column l (src lane l>>2, elem l&3)
      float t0 = __shfl(msum[0], lane >> 2);
      float t1 = __shfl(msum[1], lane >> 2);
      float t2 = __shfl(msum[2], lane >> 2);
      float t3 = __shfl(msum[3], lane >> 2);
      int sel = lane & 3;
      float val = sel == 0 ? t0 : (sel == 1 ? t1 : (sel == 2 ? t2 : t3));
      atomicAdd(&msg_tot[(size_t)node*64 + lane], val);   // 256B coalesced

      if (lane == 0) {
        atomicAdd(&out_coord[(size_t)node*3 + 0], sx);
        atomicAdd(&out_coord[(size_t)node*3 + 1], sy);
        atomicAdd(&out_coord[(size_t)node*3 + 2], sz);
      }
      start = end;
    }

    if (!hn) break;
    // ---- rotate pipeline ----
    g = gn;
    dv = nm.y;
    rx = nq.x; ry = nq.y; rz = nq.z;
    dist0 = __shfl(nq.w, cl); dist1 = __shfl(nq.w, 16 + cl);
    cf = nf_;
  }
}

// ---------------------------------------------------------------------------
// Node kernel (persistent): new_feat = node_feat + silu([f|msg]@W1n+b1)@W2n+b2
// ---------------------------------------------------------------------------
__global__ __launch_bounds__(256, 1) void egnn_node(
    const float* __restrict__ node_feat, const float* __restrict__ msg_tot,
    const float* __restrict__ w1n, const float* __restrict__ b1n,
    const float* __restrict__ w2n, const float* __restrict__ b2n,
    float* __restrict__ out_feat)
{
  __shared__ u16 w1f[4*8*64*8];   // 32KB  (n = 8*(l&15)+nt)
  __shared__ u16 w2f[4*4*64*8];   // 16KB  (n = 4*(l&15)+nt)
  __shared__ u16 a_lds[64*HS2];
  __shared__ u16 h_lds[64*HS2];
  __shared__ float b1s[128];
  __shared__ float b2s[64];

  const int t = threadIdx.x, lane = t & 63, wv = t >> 6;
  const int cl = lane & 15;
  const int row16 = wv*16 + cl;
  const int g8 = (lane >> 4) * 8;
  const int orow = wv*16 + (lane >> 4)*4;

  for (int i = t; i < 4*8*64*8; i += 256) {
    int j = i & 7, l = (i >> 3) & 63, nt = (i >> 9) & 7, kb = i >> 12;
    w1f[i] = f2bf(w1n[(kb*32 + (l >> 4)*8 + j)*128 + 8*(l & 15) + nt]);
  }
  for (int i = t; i < 4*4*64*8; i += 256) {
    int j = i & 7, l = (i >> 3) & 63, nt = (i >> 9) & 3, kb = i >> 11;
    w2f[i] = f2bf(w2n[(kb*32 + (l >> 4)*8 + j)*64 + 4*(l & 15) + nt]);
  }
  if (t < 128) b1s[t] = b1n[t];
  if (t < 64)  b2s[t] = b2n[t];

  for (int tile = blockIdx.x; tile < NT_NODE; tile += gridDim.x) {
    const int n0 = tile * 64;
    __syncthreads();                    // protect a_lds/h_lds reuse
    {
      const int nd = t >> 2, q = t & 3;
      const int gn = n0 + nd;
      u16* arow = a_lds + nd*HS2;
      if (gn < NN) {
        const float4* pf = (const float4*)(node_feat + (size_t)gn*64 + q*16);
        float4 vf = pf[0], vf2 = pf[1], vf3 = pf[2], vf4 = pf[3];
        uint4 qa = { pk2bf_t(vf.x, vf.y),  pk2bf_t(vf.z, vf.w),
                     pk2bf_t(vf2.x, vf2.y), pk2bf_t(vf2.z, vf2.w) };
        uint4 qb = { pk2bf_t(vf3.x, vf3.y), pk2bf_t(vf3.z, vf3.w),
                     pk2bf_t(vf4.x, vf4.y), pk2bf_t(vf4.z, vf4.w) };
        *(uint4*)(arow + q*16) = qa;
        *(uint4*)(arow + q*16 + 8) = qb;
        const float4* pm = (const float4*)(msg_tot + (size_t)gn*64 + q*16);
        float4 vm = pm[0], vm2 = pm[1], vm3 = pm[2], vm4 = pm[3];
        uint4 qc = { pk2bf_t(vm.x, vm.y),  pk2bf_t(vm.z, vm.w),
                     pk2bf_t(vm2.x, vm2.y), pk2bf_t(vm2.z, vm2.w) };
        uint4 qd = { pk2bf_t(vm3.x, vm3.y), pk2bf_t(vm3.z, vm3.w),
                     pk2bf_t(vm4.x, vm4.y), pk2bf_t(vm4.z, vm4.w) };
        *(uint4*)(arow + 64 + q*16) = qc;
        *(uint4*)(arow + 64 + q*16 + 8) = qd;
      } else {
        uint4 z = {0,0,0,0};
        *(uint4*)(arow + q*16) = z;  *(uint4*)(arow + q*16 + 8) = z;
        *(uint4*)(arow + 64 + q*16) = z; *(uint4*)(arow + 64 + q*16 + 8) = z;
      }
    }
    __syncthreads();
    {
      f32x4 acc[8];
      #pragma unroll
      for (int nt = 0; nt < 8; ++nt) acc[nt] = (f32x4){0.f,0.f,0.f,0.f};
      #pragma unroll
      for (int kb = 0; kb < 4; ++kb) {
        bf16x8 af = *(const bf16x8*)(a_lds + row16*HS2 + kb*32 + g8);
        #pragma unroll
        for (int nt = 0; nt < 8; ++nt) {
          bf16x8 bfv = *(const bf16x8*)(w1f + ((kb*8 + nt)*64 + lane)*8);
          acc[nt] = __builtin_amdgcn_mfma_f32_16x16x32_bf16(af, bfv, acc[nt], 0, 0, 0);
        }
      }
      #pragma unroll
      for (int r = 0; r < 4; ++r) {
        uint4 q;
        q.x = pk2bf_t(silu_f(acc[0][r] + b1s[8*cl+0]), silu_f(acc[1][r] + b1s[8*cl+1]));
        q.y = pk2bf_t(silu_f(acc[2][r] + b1s[8*cl+2]), silu_f(acc[3][r] + b1s[8*cl+3]));
        q.z = pk2bf_t(silu_f(acc[4][r] + b1s[8*cl+4]), silu_f(acc[5][r] + b1s[8*cl+5]));
        q.w = pk2bf_t(silu_f(acc[6][r] + b1s[8*cl+6]), silu_f(acc[7][r] + b1s[8*cl+7]));
        *(uint4*)(h_lds + (orow + r)*HS2 + 8*cl) = q;
      }
    }
    __syncthreads();
    {
      f32x4 acc[4];
      #pragma unroll
      for (int nt = 0; nt < 4; ++nt) acc[nt] = (f32x4){0.f,0.f,0.f,0.f};
      #pragma unroll
      for (int kb = 0; kb < 4; ++kb) {
        bf16x8 af = *(const bf16x8*)(h_lds + row16*HS2 + kb*32 + g8);
        #pragma unroll
        for (int nt = 0; nt < 4; ++nt) {
          bf16x8 bfv = *(const bf16x8*)(w2f + ((kb*4 + nt)*64 + lane)*8);
          acc[nt] = __builtin_amdgcn_mfma_f32_16x16x32_bf16(af, bfv, acc[nt], 0, 0, 0);
        }
      }
      #pragma unroll
      for (int r = 0; r < 4; ++r) {
        int row = orow + r, gn = n0 + row;
        if (gn < NN) {
          float4 base = *(const float4*)(node_feat + (size_t)gn*64 + 4*cl);
          float4 o;
          o.x = acc[0][r] + b2s[4*cl+0] + base.x;
          o.y = acc[1][r] + b2s[4*cl+1] + base.y;
          o.z = acc[2][r] + b2s[4*cl+2] + base.z;
          o.w = acc[3][r] + b2s[4*cl+3] + base.w;
          *(float4*)(out_feat + (size_t)gn*64 + 4*cl) = o;
        }
      }
    }
  }
}

extern "C" void kernel_launch(void* const* d_in, const int* in_sizes, int n_in,
                              void* d_out, int out_size, void* d_ws, size_t ws_size,
                              hipStream_t stream) {
  (void)in_sizes; (void)n_in; (void)out_size;
  const float* node_feat = (const float*)d_in[0];
  const float* coord     = (const float*)d_in[1];
  const float* edge_feat = (const float*)d_in[2];
  const int*   eidx      = (const int*)d_in[3];
  const float* w1_msg    = (const float*)d_in[4];
  const float* w2_msg    = (const float*)d_in[5];
  const float* w1_mov    = (const float*)d_in[6];
  const float* w2_mov    = (const float*)d_in[7];
  const float* w1n       = (const float*)d_in[9];
  const float* b1n       = (const float*)d_in[10];
  const float* w2n       = (const float*)d_in[11];
  const float* b2n       = (const float*)d_in[12];

  float* out_feat  = (float*)d_out;
  float* out_coord = out_feat + (size_t)NN * 64;

  // workspace layout (all 16B aligned)
  int*    count   = (int*)d_ws;                          // 50048
  int*    cursor  = count + 50048;                       // 50048
  int*    bsum    = cursor + 50048;                      // 1024
  int*    boff    = bsum + 1024;                         // 1024 (pad)
  float*  msg_tot = (float*)(boff + 1024);               // 3.2M floats (12.8MB)
  int4*   meta    = (int4*)(msg_tot + (size_t)NN*64);    // 1.6M int4 (25.6MB)
  float4* geo     = (float4*)(meta + E_TOT);             // 1.6M float4 (25.6MB)
  u16*    nf16    = (u16*)(geo + E_TOT);                 // 3.2M u16 (6.4MB)
  const size_t need16 = (size_t)((char*)(nf16 + (size_t)NN*64) - (char*)d_ws);
  const int use16 = ws_size >= need16 ? 1 : 0;

  hipMemsetAsync(count, 0, NN * sizeof(int), stream);
  prep_k<<<2048, 256, 0, stream>>>(node_feat, nf16, eidx, count,
                                   msg_tot, coord, out_coord, use16);
  scanA_k<<<NB, 256, 0, stream>>>(count, bsum);
  scanC_k<<<NB, 256, 0, stream>>>(count, bsum, cursor);
  scatter_k<<<2048, 256, 0, stream>>>(eidx, coord, cursor, meta, geo);
  egnn_edge<<<256, 512, 0, stream>>>(node_feat, edge_feat, meta, geo,
      w1_msg, w2_msg, w1_mov, w2_mov, nf16, use16, msg_tot, out_coord);
  egnn_node<<<256, 256, 0, stream>>>(node_feat, msg_tot,
      w1n, b1n, w2n, b2n, out_feat);
}

// Round 17
// 443.900 us; speedup vs baseline: 2.1662x; 1.1042x over previous
//
#include <hip/hip_runtime.h>
#include <hip/hip_bf16.h>

#define E_TOT   1600000
#define NN      50000
#define K1      176     // msg MLP input dim (2*64+32+16)
#define H1      128     // MSG_HID
#define HS2     136     // act row stride (ushorts), 272B, 16B aligned
#define NGC     (E_TOT / 32)   // 50000 exact 32-edge chunks
#define NB      196            // scan blocks (196*256 >= 50001)
#define NT_NODE ((NN + 63) / 64)
#define EW      8              // waves per edge-kernel block (512 thr — >512 spills!)

typedef __attribute__((ext_vector_type(8))) short bf16x8;
typedef __attribute__((ext_vector_type(4))) float f32x4;
typedef unsigned short u16;
typedef unsigned int u32;

__device__ __forceinline__ u16 f2bf(float x) {
  return __builtin_bit_cast(u16, __float2bfloat16(x));   // RNE (prep paths)
}
__device__ __forceinline__ u32 pk2bf(float lo, float hi) {
  return (u32)f2bf(lo) | ((u32)f2bf(hi) << 16);
}
// truncating packs for activations (error <1 ulp bf16; passed at absmax 4.0)
__device__ __forceinline__ u32 pk2bf_t(float lo, float hi) {
  return (__builtin_bit_cast(u32, lo) >> 16) |
         (__builtin_bit_cast(u32, hi) & 0xFFFF0000u);
}
__device__ __forceinline__ u16 f2bf_t(float x) {
  return (u16)(__builtin_bit_cast(u32, x) >> 16);
}
// fast silu: v_rcp_f32 instead of the IEEE div sequence (proven -23% r16).
__device__ __forceinline__ float silu_f(float x) {
  return x * __builtin_amdgcn_rcpf(1.0f + __expf(-x));
}

__device__ __forceinline__ bf16x8 ldf8(const float* __restrict__ p) {
  float4 a = ((const float4*)p)[0];
  float4 b = ((const float4*)p)[1];
  bf16x8 r;
  r[0] = (short)f2bf(a.x); r[1] = (short)f2bf(a.y);
  r[2] = (short)f2bf(a.z); r[3] = (short)f2bf(a.w);
  r[4] = (short)f2bf(b.x); r[5] = (short)f2bf(b.y);
  r[6] = (short)f2bf(b.z); r[7] = (short)f2bf(b.w);
  return r;
}

struct Feats { bf16x8 s0a, s0b, s1a, s1b, d0a, d0b, d1a, d1b, e0, e1; };

__device__ __forceinline__ void load_feats(Feats& f, int use16,
    const u16* __restrict__ nf16, const float* __restrict__ nf,
    const float* __restrict__ ef,
    int s0, int s1, int d0, int d1, int e0i, int e1i, int g8)
{
  if (use16) {
    f.s0a = *(const bf16x8*)(nf16 + (size_t)s0*64 + g8);
    f.s0b = *(const bf16x8*)(nf16 + (size_t)s0*64 + 32 + g8);
    f.s1a = *(const bf16x8*)(nf16 + (size_t)s1*64 + g8);
    f.s1b = *(const bf16x8*)(nf16 + (size_t)s1*64 + 32 + g8);
    f.d0a = *(const bf16x8*)(nf16 + (size_t)d0*64 + g8);
    f.d0b = *(const bf16x8*)(nf16 + (size_t)d0*64 + 32 + g8);
    f.d1a = *(const bf16x8*)(nf16 + (size_t)d1*64 + g8);
    f.d1b = *(const bf16x8*)(nf16 + (size_t)d1*64 + 32 + g8);
  } else {
    f.s0a = ldf8(nf + (size_t)s0*64 + g8);
    f.s0b = ldf8(nf + (size_t)s0*64 + 32 + g8);
    f.s1a = ldf8(nf + (size_t)s1*64 + g8);
    f.s1b = ldf8(nf + (size_t)s1*64 + 32 + g8);
    f.d0a = ldf8(nf + (size_t)d0*64 + g8);
    f.d0b = ldf8(nf + (size_t)d0*64 + 32 + g8);
    f.d1a = ldf8(nf + (size_t)d1*64 + g8);
    f.d1b = ldf8(nf + (size_t)d1*64 + 32 + g8);
  }
  if (g8 < 16) {                      // edge_feat fp32 (64B rows = same granule)
    f.e0 = ldf8(ef + (size_t)e0i*16 + g8);
    f.e1 = ldf8(ef + (size_t)e1i*16 + g8);
  } else { f.e0 = (bf16x8){0,0,0,0,0,0,0,0}; f.e1 = f.e0; }
}

// ---------------------------------------------------------------------------
// Fused prep: node cvt + dst histogram + msg_tot zero + out_coord=coord.
// ---------------------------------------------------------------------------
__global__ void prep_k(const float* __restrict__ nf, u16* __restrict__ nf16,
                       const int* __restrict__ eidx, int* __restrict__ count,
                       float* __restrict__ msg_tot,
                       const float* __restrict__ coord, float* __restrict__ out_coord,
                       int use16) {
  const int tid = blockIdx.x * blockDim.x + threadIdx.x;
  const int stride = gridDim.x * blockDim.x;
  if (use16) {
    for (int i = tid; i < NN*64/4; i += stride) {
      float4 v = ((const float4*)nf)[i];
      uint2 p = { pk2bf(v.x, v.y), pk2bf(v.z, v.w) };
      ((uint2*)nf16)[i] = p;
    }
  }
  const float4 z4 = {0.f, 0.f, 0.f, 0.f};
  for (int i = tid; i < NN*64/4; i += stride) ((float4*)msg_tot)[i] = z4;
  for (int i = tid; i < NN*3; i += stride) out_coord[i] = coord[i];
  for (int i = tid; i < E_TOT; i += stride) atomicAdd(&count[eidx[E_TOT + i]], 1);
}

__global__ __launch_bounds__(256) void scanA_k(const int* __restrict__ count,
                                               int* __restrict__ bsum) {
  __shared__ int sm[256];
  int idx = blockIdx.x * 256 + threadIdx.x;
  sm[threadIdx.x] = (idx < NN) ? count[idx] : 0;
  __syncthreads();
  for (int off = 128; off > 0; off >>= 1) {
    if (threadIdx.x < off) sm[threadIdx.x] += sm[threadIdx.x + off];
    __syncthreads();
  }
  if (threadIdx.x == 0) bsum[blockIdx.x] = sm[0];
}

// scanC (merged scanB): each block redoes the tiny block-sum prefix locally.
__global__ __launch_bounds__(256) void scanC_k(const int* __restrict__ count,
                                               const int* __restrict__ bsum,
                                               int* __restrict__ cursor) {
  __shared__ int sb[256];
  __shared__ int sm[256];
  const int t = threadIdx.x;
  int vb = (t < NB) ? bsum[t] : 0;
  sb[t] = vb; __syncthreads();
  for (int off = 1; off < 256; off <<= 1) {
    int x = (t >= off) ? sb[t - off] : 0;
    __syncthreads();
    sb[t] += x;
    __syncthreads();
  }
  const int boff = sb[blockIdx.x] - bsum[blockIdx.x];   // exclusive prefix
  __syncthreads();
  int idx = blockIdx.x * 256 + t;
  int v = (idx < NN) ? count[idx] : 0;
  sm[t] = v; __syncthreads();
  for (int off = 1; off < 256; off <<= 1) {
    int x = (t >= off) ? sm[t - off] : 0;
    __syncthreads();
    sm[t] += x;
    __syncthreads();
  }
  if (idx < NN) cursor[idx] = boff + sm[t] - v;
}

// scatter: write dst-sorted sd {src,dst} + eid + geo {rel.xyz, dist}
__global__ void scatter_k(const int* __restrict__ eidx,
                          const float* __restrict__ coord,
                          int* __restrict__ cursor,
                          int2* __restrict__ sd, int* __restrict__ eid,
                          float4* __restrict__ geo) {
  int i = blockIdx.x * blockDim.x + threadIdx.x;
  int stride = gridDim.x * blockDim.x;
  for (; i < E_TOT; i += stride) {
    int s = eidx[i];
    int d = eidx[E_TOT + i];
    int pos = atomicAdd(&cursor[d], 1);
    float rx = coord[(size_t)d*3+0] - coord[(size_t)s*3+0];
    float ry = coord[(size_t)d*3+1] - coord[(size_t)s*3+1];
    float rz = coord[(size_t)d*3+2] - coord[(size_t)s*3+2];
    float dist = sqrtf(rx*rx + ry*ry + rz*rz);
    sd[pos]  = make_int2(s, d);
    eid[pos] = i;
    geo[pos] = make_float4(rx, ry, rz, dist);
  }
}

// ---------------------------------------------------------------------------
// Edge kernel v17 (= r16 + slim meta (int2+int) + whole-chunk fast path in
// the segmented reduction). 512thr/(512,2); weights in LDS; coalesced
// sd/eid/geo streams; packed epilogues; fast-rcp silu; 256B msg atomics.
// ---------------------------------------------------------------------------
__global__ __launch_bounds__(512, 2) void egnn_edge(
    const float* __restrict__ node_feat, const float* __restrict__ edge_feat,
    const int2* __restrict__ sd, const int* __restrict__ eid,
    const float4* __restrict__ geo,
    const float* __restrict__ w1_msg, const float* __restrict__ w2_msg,
    const float* __restrict__ w1_mov, const float* __restrict__ w2_mov,
    const u16* __restrict__ nf16, int use16,
    float* __restrict__ msg_tot, float* __restrict__ out_coord)
{
  __shared__ u16 w1f[6*8*64*8];     // 48KB
  __shared__ u16 w2f[4*4*64*8];     // 16KB
  __shared__ u16 w3f[2*4*64*8];     // 8KB
  __shared__ u16 act[EW][32*HS2];   // 69.6KB (total 141.6KB)

  const int t = threadIdx.x;
  const int lane = t & 63;
  const int wv = t >> 6;              // 0..7
  const int cl = lane & 15;
  const int g8 = (lane >> 4) * 8;
  const int orow4 = (lane >> 4) * 4;
  const int el = lane & 31;

  for (int i = t; i < 6*8*64*8; i += 512) {
    int j = i & 7, l = (i >> 3) & 63, nt = (i >> 9) & 7, kb = i >> 12;
    int k = kb*32 + (l >> 4)*8 + j;
    w1f[i] = f2bf(k < K1 ? w1_msg[k*H1 + 8*(l & 15) + nt] : 0.0f);
  }
  for (int i = t; i < 4*4*64*8; i += 512) {
    int j = i & 7, l = (i >> 3) & 63, nt = (i >> 9) & 3, kb = i >> 11;
    w2f[i] = f2bf(w2_msg[(kb*32 + (l >> 4)*8 + j)*64 + 4*(l & 15) + nt]);
  }
  for (int i = t; i < 2*4*64*8; i += 512) {
    int j = i & 7, l = (i >> 3) & 63, nt = (i >> 9) & 3, kb = i >> 11;
    w3f[i] = f2bf(w1_mov[(kb*32 + (l >> 4)*8 + j)*64 + 4*(l & 15) + nt]);
  }
  float w2m_r[4];
  #pragma unroll
  for (int nt = 0; nt < 4; ++nt) w2m_r[nt] = w2_mov[4*cl + nt];

  __syncthreads();                    // weights ready; no barriers after this

  u16* const myact = &act[wv][0];
  const int NW = gridDim.x * EW;

  int g = blockIdx.x * EW + wv;
  if (g >= NGC) return;

  // ---- prologue: coalesced sd/eid/geo + feature gathers ----
  int2  mm = sd[g*32 + el];
  int   me = eid[g*32 + el];
  float4 qq = geo[g*32 + el];
  int dv = mm.y;
  float rx = qq.x, ry = qq.y, rz = qq.z;
  float dist0 = __shfl(qq.w, cl), dist1 = __shfl(qq.w, 16 + cl);
  Feats cf;
  {
    int s0 = __shfl(mm.x, cl), s1 = __shfl(mm.x, 16 + cl);
    int d0 = __shfl(mm.y, cl), d1 = __shfl(mm.y, 16 + cl);
    int e0i = __shfl(me, cl), e1i = __shfl(me, 16 + cl);
    load_feats(cf, use16, nf16, node_feat, edge_feat,
               s0, s1, d0, d1, e0i, e1i, g8);
  }

  while (true) {
    const int gn = g + NW;
    const bool hn = gn < NGC;

    // ---- stage 0: next chunk's sd/eid/geo (coalesced, no chain) ----
    int2 nm = make_int2(0,0);
    int  ne = 0;
    float4 nq = make_float4(0.f,0.f,0.f,0.f);
    if (hn) { nm = sd[gn*32 + el]; ne = eid[gn*32 + el]; nq = geo[gn*32 + el]; }

    // ---- rbf fragments (current chunk) ----
    bf16x8 rbf0, rbf1;
    #pragma unroll
    for (int j = 0; j < 8; ++j) {
      float c = (float)(g8 + j) * (10.0f / 31.0f);
      float u0 = dist0 - c, u1 = dist1 - c;
      rbf0[j] = (short)f2bf_t(__expf(-10.0f * u0 * u0));
      rbf1[j] = (short)f2bf_t(__expf(-10.0f * u1 * u1));
    }

    // ---- GEMM1: h = silu(m_in @ W1)  [32x192]@[192x128] ----
    f32x4 acc1[2][8];
    #pragma unroll
    for (int rt = 0; rt < 2; ++rt)
      #pragma unroll
      for (int nt = 0; nt < 8; ++nt) acc1[rt][nt] = (f32x4){0.f,0.f,0.f,0.f};
    #pragma unroll
    for (int kb = 0; kb < 6; ++kb) {
      bf16x8 af0, af1;
      if      (kb == 0) { af0 = cf.s0a; af1 = cf.s1a; }
      else if (kb == 1) { af0 = cf.s0b; af1 = cf.s1b; }
      else if (kb == 2) { af0 = cf.d0a; af1 = cf.d1a; }
      else if (kb == 3) { af0 = cf.d0b; af1 = cf.d1b; }
      else if (kb == 4) { af0 = rbf0;   af1 = rbf1;   }
      else              { af0 = cf.e0;  af1 = cf.e1;  }
      #pragma unroll
      for (int nt = 0; nt < 8; ++nt) {
        bf16x8 bw = *(const bf16x8*)(w1f + ((kb*8 + nt)*64 + lane)*8);
        acc1[0][nt] = __builtin_amdgcn_mfma_f32_16x16x32_bf16(af0, bw, acc1[0][nt], 0, 0, 0);
        acc1[1][nt] = __builtin_amdgcn_mfma_f32_16x16x32_bf16(af1, bw, acc1[1][nt], 0, 0, 0);
      }
    }
    // packed epilogue: lane holds h[row][8*cl .. 8*cl+7] for 8 rows
    #pragma unroll
    for (int rt = 0; rt < 2; ++rt)
      #pragma unroll
      for (int r = 0; r < 4; ++r) {
        uint4 q;
        q.x = pk2bf_t(silu_f(acc1[rt][0][r]), silu_f(acc1[rt][1][r]));
        q.y = pk2bf_t(silu_f(acc1[rt][2][r]), silu_f(acc1[rt][3][r]));
        q.z = pk2bf_t(silu_f(acc1[rt][4][r]), silu_f(acc1[rt][5][r]));
        q.w = pk2bf_t(silu_f(acc1[rt][6][r]), silu_f(acc1[rt][7][r]));
        *(uint4*)(myact + (rt*16 + orow4 + r)*HS2 + 8*cl) = q;
      }
    asm volatile("" ::: "memory");    // h-writes before h-reads (program order)

    // ---- GEMM2: msg = silu(h @ W2)  [32x128]@[128x64] ----
    f32x4 acc2[2][4];
    #pragma unroll
    for (int rt = 0; rt < 2; ++rt)
      #pragma unroll
      for (int nt = 0; nt < 4; ++nt) acc2[rt][nt] = (f32x4){0.f,0.f,0.f,0.f};
    #pragma unroll
    for (int kb = 0; kb < 4; ++kb) {
      bf16x8 a0 = *(const bf16x8*)(myact + cl*HS2 + kb*32 + g8);
      bf16x8 a1 = *(const bf16x8*)(myact + (16 + cl)*HS2 + kb*32 + g8);
      #pragma unroll
      for (int nt = 0; nt < 4; ++nt) {
        bf16x8 bw = *(const bf16x8*)(w2f + ((kb*4 + nt)*64 + lane)*8);
        acc2[0][nt] = __builtin_amdgcn_mfma_f32_16x16x32_bf16(a0, bw, acc2[0][nt], 0, 0, 0);
        acc2[1][nt] = __builtin_amdgcn_mfma_f32_16x16x32_bf16(a1, bw, acc2[1][nt], 0, 0, 0);
      }
    }
    asm volatile("" ::: "memory");
    // mval regs (col = 4*cl+nt) + packed m -> act cols 0..63
    float mval[2][4][4];
    #pragma unroll
    for (int rt = 0; rt < 2; ++rt)
      #pragma unroll
      for (int r = 0; r < 4; ++r) {
        #pragma unroll
        for (int nt = 0; nt < 4; ++nt) mval[rt][nt][r] = silu_f(acc2[rt][nt][r]);
        uint2 q;
        q.x = pk2bf_t(mval[rt][0][r], mval[rt][1][r]);
        q.y = pk2bf_t(mval[rt][2][r], mval[rt][3][r]);
        *(uint2*)(myact + (rt*16 + orow4 + r)*HS2 + 4*cl) = q;
      }
    asm volatile("" ::: "memory");    // m-writes before m-reads

    // ---- stage 2: next chunk's feature gathers ----
    Feats nf_;
    if (hn) {
      int s0 = __shfl(nm.x, cl), s1 = __shfl(nm.x, 16 + cl);
      int d0 = __shfl(nm.y, cl), d1 = __shfl(nm.y, 16 + cl);
      int e0i = __shfl(ne, cl), e1i = __shfl(ne, 16 + cl);
      load_feats(nf_, use16, nf16, node_feat, edge_feat,
                 s0, s1, d0, d1, e0i, e1i, g8);
    }

    // ---- GEMM3: s = silu(msg @ W3) @ w2_mov ----
    f32x4 acc3[2][4];
    #pragma unroll
    for (int rt = 0; rt < 2; ++rt)
      #pragma unroll
      for (int nt = 0; nt < 4; ++nt) acc3[rt][nt] = (f32x4){0.f,0.f,0.f,0.f};
    #pragma unroll
    for (int kb = 0; kb < 2; ++kb) {
      bf16x8 a0 = *(const bf16x8*)(myact + cl*HS2 + kb*32 + g8);
      bf16x8 a1 = *(const bf16x8*)(myact + (16 + cl)*HS2 + kb*32 + g8);
      #pragma unroll
      for (int nt = 0; nt < 4; ++nt) {
        bf16x8 bw = *(const bf16x8*)(w3f + ((kb*4 + nt)*64 + lane)*8);
        acc3[0][nt] = __builtin_amdgcn_mfma_f32_16x16x32_bf16(a0, bw, acc3[0][nt], 0, 0, 0);
        acc3[1][nt] = __builtin_amdgcn_mfma_f32_16x16x32_bf16(a1, bw, acc3[1][nt], 0, 0, 0);
      }
    }
    float prt[2][4];
    #pragma unroll
    for (int rt = 0; rt < 2; ++rt)
      #pragma unroll
      for (int r = 0; r < 4; ++r) prt[rt][r] = 0.f;
    #pragma unroll
    for (int nt = 0; nt < 4; ++nt)
      #pragma unroll
      for (int rt = 0; rt < 2; ++rt)
        #pragma unroll
        for (int r = 0; r < 4; ++r)
          prt[rt][r] += silu_f(acc3[rt][nt][r]) * w2m_r[nt];
    #pragma unroll
    for (int off = 1; off < 16; off <<= 1)
      #pragma unroll
      for (int rt = 0; rt < 2; ++rt)
        #pragma unroll
        for (int r = 0; r < 4; ++r) prt[rt][r] += __shfl_xor(prt[rt][r], off, 64);

    // per-row rel vectors (broadcast once)
    float rxv[2][4], ryv[2][4], rzv[2][4];
    #pragma unroll
    for (int rt = 0; rt < 2; ++rt)
      #pragma unroll
      for (int r = 0; r < 4; ++r) {
        int row = rt*16 + orow4 + r;
        rxv[rt][r] = __shfl(rx, row);
        ryv[rt][r] = __shfl(ry, row);
        rzv[rt][r] = __shfl(rz, row);
      }

    // ---- segmented aggregation over dst-runs (rows sorted by dst) ----
    int start = 0;
    while (start < 32) {
      int node = __shfl(dv, start);
      unsigned long long b = __ballot(dv == node);
      unsigned m32 = (unsigned)b;
      unsigned rest = ~m32 & (0xFFFFFFFFu << start);
      int end = rest ? (__ffs(rest) - 1) : 32;

      float msum[4] = {0.f, 0.f, 0.f, 0.f};
      float sx = 0.f, sy = 0.f, sz = 0.f;
      if (start == 0 && end == 32) {
        // whole-chunk fast path (~37% of chunks): no masks
        #pragma unroll
        for (int rt = 0; rt < 2; ++rt)
          #pragma unroll
          for (int r = 0; r < 4; ++r) {
            #pragma unroll
            for (int nt = 0; nt < 4; ++nt) msum[nt] += mval[rt][nt][r];
            float s = prt[rt][r];
            sx += rxv[rt][r] * s; sy += ryv[rt][r] * s; sz += rzv[rt][r] * s;
          }
      } else {
        #pragma unroll
        for (int rt = 0; rt < 2; ++rt)
          #pragma unroll
          for (int r = 0; r < 4; ++r) {
            int row = rt*16 + orow4 + r;
            float mk = (row >= start && row < end) ? 1.0f : 0.0f;
            #pragma unroll
            for (int nt = 0; nt < 4; ++nt) msum[nt] += mval[rt][nt][r] * mk;
            float s = prt[rt][r] * mk;
            sx += rxv[rt][r] * s; sy += ryv[rt][r] * s; sz += rzv[rt][r] * s;
          }
      }
      #pragma unroll
      for (int nt = 0; nt < 4; ++nt) {
        msum[nt] += __shfl_xor(msum[nt], 16, 64);
        msum[nt] += __shfl_xor(msum[nt], 32, 64);
      }
      sx += __shfl_xor(sx, 16, 64); sx += __shfl_xor(sx, 32, 64);
      sy += __shfl_xor(sy, 16, 64); sy += __shfl_xor(sy, 32, 64);
      sz += __shfl_xor(sz, 16, 64); sz += __shfl_xor(sz, 32, 64);

      // register transpose: lane l takes column l (src lane l>>2, elem l&3)
      float t0 = __shfl(msum[0], lane >> 2);
      float t1 = __shfl(msum[1], lane >> 2);
      float t2 = __shfl(msum[2], lane >> 2);
      float t3 = __shfl(msum[3], lane >> 2);
      int sel = lane & 3;
      float val = sel == 0 ? t0 : (sel == 1 ? t1 : (sel == 2 ? t2 : t3));
      atomicAdd(&msg_tot[(size_t)node*64 + lane], val);   // 256B coalesced

      if (lane == 0) {
        atomicAdd(&out_coord[(size_t)node*3 + 0], sx);
        atomicAdd(&out_coord[(size_t)node*3 + 1], sy);
        atomicAdd(&out_coord[(size_t)node*3 + 2], sz);
      }
      start = end;
    }

    if (!hn) break;
    // ---- rotate pipeline ----
    g = gn;
    dv = nm.y;
    rx = nq.x; ry = nq.y; rz = nq.z;
    dist0 = __shfl(nq.w, cl); dist1 = __shfl(nq.w, 16 + cl);
    cf = nf_;
  }
}

// ---------------------------------------------------------------------------
// Node kernel (persistent): new_feat = node_feat + silu([f|msg]@W1n+b1)@W2n+b2
// ---------------------------------------------------------------------------
__global__ __launch_bounds__(256, 1) void egnn_node(
    const float* __restrict__ node_feat, const float* __restrict__ msg_tot,
    const float* __restrict__ w1n, const float* __restrict__ b1n,
    const float* __restrict__ w2n, const float* __restrict__ b2n,
    float* __restrict__ out_feat)
{
  __shared__ u16 w1f[4*8*64*8];   // 32KB  (n = 8*(l&15)+nt)
  __shared__ u16 w2f[4*4*64*8];   // 16KB  (n = 4*(l&15)+nt)
  __shared__ u16 a_lds[64*HS2];
  __shared__ u16 h_lds[64*HS2];
  __shared__ float b1s[128];
  __shared__ float b2s[64];

  const int t = threadIdx.x, lane = t & 63, wv = t >> 6;
  const int cl = lane & 15;
  const int row16 = wv*16 + cl;
  const int g8 = (lane >> 4) * 8;
  const int orow = wv*16 + (lane >> 4)*4;

  for (int i = t; i < 4*8*64*8; i += 256) {
    int j = i & 7, l = (i >> 3) & 63, nt = (i >> 9) & 7, kb = i >> 12;
    w1f[i] = f2bf(w1n[(kb*32 + (l >> 4)*8 + j)*128 + 8*(l & 15) + nt]);
  }
  for (int i = t; i < 4*4*64*8; i += 256) {
    int j = i & 7, l = (i >> 3) & 63, nt = (i >> 9) & 3, kb = i >> 11;
    w2f[i] = f2bf(w2n[(kb*32 + (l >> 4)*8 + j)*64 + 4*(l & 15) + nt]);
  }
  if (t < 128) b1s[t] = b1n[t];
  if (t < 64)  b2s[t] = b2n[t];

  for (int tile = blockIdx.x; tile < NT_NODE; tile += gridDim.x) {
    const int n0 = tile * 64;
    __syncthreads();                    // protect a_lds/h_lds reuse
    {
      const int nd = t >> 2, q = t & 3;
      const int gn = n0 + nd;
      u16* arow = a_lds + nd*HS2;
      if (gn < NN) {
        const float4* pf = (const float4*)(node_feat + (size_t)gn*64 + q*16);
        float4 vf = pf[0], vf2 = pf[1], vf3 = pf[2], vf4 = pf[3];
        uint4 qa = { pk2bf_t(vf.x, vf.y),  pk2bf_t(vf.z, vf.w),
                     pk2bf_t(vf2.x, vf2.y), pk2bf_t(vf2.z, vf2.w) };
        uint4 qb = { pk2bf_t(vf3.x, vf3.y), pk2bf_t(vf3.z, vf3.w),
                     pk2bf_t(vf4.x, vf4.y), pk2bf_t(vf4.z, vf4.w) };
        *(uint4*)(arow + q*16) = qa;
        *(uint4*)(arow + q*16 + 8) = qb;
        const float4* pm = (const float4*)(msg_tot + (size_t)gn*64 + q*16);
        float4 vm = pm[0], vm2 = pm[1], vm3 = pm[2], vm4 = pm[3];
        uint4 qc = { pk2bf_t(vm.x, vm.y),  pk2bf_t(vm.z, vm.w),
                     pk2bf_t(vm2.x, vm2.y), pk2bf_t(vm2.z, vm2.w) };
        uint4 qd = { pk2bf_t(vm3.x, vm3.y), pk2bf_t(vm3.z, vm3.w),
                     pk2bf_t(vm4.x, vm4.y), pk2bf_t(vm4.z, vm4.w) };
        *(uint4*)(arow + 64 + q*16) = qc;
        *(uint4*)(arow + 64 + q*16 + 8) = qd;
      } else {
        uint4 z = {0,0,0,0};
        *(uint4*)(arow + q*16) = z;  *(uint4*)(arow + q*16 + 8) = z;
        *(uint4*)(arow + 64 + q*16) = z; *(uint4*)(arow + 64 + q*16 + 8) = z;
      }
    }
    __syncthreads();
    {
      f32x4 acc[8];
      #pragma unroll
      for (int nt = 0; nt < 8; ++nt) acc[nt] = (f32x4){0.f,0.f,0.f,0.f};
      #pragma unroll
      for (int kb = 0; kb < 4; ++kb) {
        bf16x8 af = *(const bf16x8*)(a_lds + row16*HS2 + kb*32 + g8);
        #pragma unroll
        for (int nt = 0; nt < 8; ++nt) {
          bf16x8 bfv = *(const bf16x8*)(w1f + ((kb*8 + nt)*64 + lane)*8);
          acc[nt] = __builtin_amdgcn_mfma_f32_16x16x32_bf16(af, bfv, acc[nt], 0, 0, 0);
        }
      }
      #pragma unroll
      for (int r = 0; r < 4; ++r) {
        uint4 q;
        q.x = pk2bf_t(silu_f(acc[0][r] + b1s[8*cl+0]), silu_f(acc[1][r] + b1s[8*cl+1]));
        q.y = pk2bf_t(silu_f(acc[2][r] + b1s[8*cl+2]), silu_f(acc[3][r] + b1s[8*cl+3]));
        q.z = pk2bf_t(silu_f(acc[4][r] + b1s[8*cl+4]), silu_f(acc[5][r] + b1s[8*cl+5]));
        q.w = pk2bf_t(silu_f(acc[6][r] + b1s[8*cl+6]), silu_f(acc[7][r] + b1s[8*cl+7]));
        *(uint4*)(h_lds + (orow + r)*HS2 + 8*cl) = q;
      }
    }
    __syncthreads();
    {
      f32x4 acc[4];
      #pragma unroll
      for (int nt = 0; nt < 4; ++nt) acc[nt] = (f32x4){0.f,0.f,0.f,0.f};
      #pragma unroll
      for (int kb = 0; kb < 4; ++kb) {
        bf16x8 af = *(const bf16x8*)(h_lds + row16*HS2 + kb*32 + g8);
        #pragma unroll
        for (int nt = 0; nt < 4; ++nt) {
          bf16x8 bfv = *(const bf16x8*)(w2f + ((kb*4 + nt)*64 + lane)*8);
          acc[nt] = __builtin_amdgcn_mfma_f32_16x16x32_bf16(af, bfv, acc[nt], 0, 0, 0);
        }
      }
      #pragma unroll
      for (int r = 0; r < 4; ++r) {
        int row = orow + r, gn = n0 + row;
        if (gn < NN) {
          float4 base = *(const float4*)(node_feat + (size_t)gn*64 + 4*cl);
          float4 o;
          o.x = acc[0][r] + b2s[4*cl+0] + base.x;
          o.y = acc[1][r] + b2s[4*cl+1] + base.y;
          o.z = acc[2][r] + b2s[4*cl+2] + base.z;
          o.w = acc[3][r] + b2s[4*cl+3] + base.w;
          *(float4*)(out_feat + (size_t)gn*64 + 4*cl) = o;
        }
      }
    }
  }
}

extern "C" void kernel_launch(void* const* d_in, const int* in_sizes, int n_in,
                              void* d_out, int out_size, void* d_ws, size_t ws_size,
                              hipStream_t stream) {
  (void)in_sizes; (void)n_in; (void)out_size;
  const float* node_feat = (const float*)d_in[0];
  const float* coord     = (const float*)d_in[1];
  const float* edge_feat = (const float*)d_in[2];
  const int*   eidx      = (const int*)d_in[3];
  const float* w1_msg    = (const float*)d_in[4];
  const float* w2_msg    = (const float*)d_in[5];
  const float* w1_mov    = (const float*)d_in[6];
  const float* w2_mov    = (const float*)d_in[7];
  const float* w1n       = (const float*)d_in[9];
  const float* b1n       = (const float*)d_in[10];
  const float* w2n       = (const float*)d_in[11];
  const float* b2n       = (const float*)d_in[12];

  float* out_feat  = (float*)d_out;
  float* out_coord = out_feat + (size_t)NN * 64;

  // workspace layout (all 16B aligned)
  int*    count   = (int*)d_ws;                          // 50048
  int*    cursor  = count + 50048;                       // 50048
  int*    bsum    = cursor + 50048;                      // 1024
  int*    boff    = bsum + 1024;                         // 1024 (pad)
  float*  msg_tot = (float*)(boff + 1024);               // 3.2M floats (12.8MB)
  int2*   sd      = (int2*)(msg_tot + (size_t)NN*64);    // 1.6M int2 (12.8MB)
  int*    eid     = (int*)(sd + E_TOT);                  // 1.6M int (6.4MB)
  float4* geo     = (float4*)(eid + E_TOT);              // 1.6M float4 (25.6MB)
  u16*    nf16    = (u16*)(geo + E_TOT);                 // 3.2M u16 (6.4MB)
  const size_t need16 = (size_t)((char*)(nf16 + (size_t)NN*64) - (char*)d_ws);
  const int use16 = ws_size >= need16 ? 1 : 0;

  hipMemsetAsync(count, 0, NN * sizeof(int), stream);
  prep_k<<<2048, 256, 0, stream>>>(node_feat, nf16, eidx, count,
                                   msg_tot, coord, out_coord, use16);
  scanA_k<<<NB, 256, 0, stream>>>(count, bsum);
  scanC_k<<<NB, 256, 0, stream>>>(count, bsum, cursor);
  scatter_k<<<2048, 256, 0, stream>>>(eidx, coord, cursor, sd, eid, geo);
  egnn_edge<<<256, 512, 0, stream>>>(node_feat, edge_feat, sd, eid, geo,
      w1_msg, w2_msg, w1_mov, w2_mov, nf16, use16, msg_tot, out_coord);
  egnn_node<<<256, 256, 0, stream>>>(node_feat, msg_tot,
      w1n, b1n, w2n, b2n, out_feat);
}